// Round 1
// baseline (1378.268 us; speedup 1.0000x reference)
//
#include <hip/hip_runtime.h>
#include <hip/hip_bf16.h>
#include <cstdint>

#define N_NODES 100000
#define N_EDGES 1600000
#define N_TOT   1700000   // edges + self loops
#define HEADS   4
#define CH      64
#define HC      256       // HEADS*CH
#define NEG     0.2f
#define BNEPS   1e-5f

static __device__ __forceinline__ float lrelu(float x) {
    return x > 0.f ? x : NEG * x;
}

// ---------------- edge dtype detection (int32 vs int64) ----------------
__global__ void detect_dtype(const int* ei32, int* flag) {
    int l = threadIdx.x;
    int v = ei32[2 * l + 1];
    unsigned long long b = __ballot(v == 0);
    if (l == 0) *flag = (__popcll(b) >= 48) ? 1 : 0;
}

static __device__ __forceinline__ int edge_at(const void* ei, int is64, long long pos) {
    if (is64) return (int)((const long long*)ei)[pos];
    return ((const int*)ei)[pos];
}

// ---------------- CSR build ----------------
__global__ void hist_k(const void* ei, const int* flag, int* counts) {
    int e = blockIdx.x * blockDim.x + threadIdx.x;
    if (e >= N_TOT) return;
    int is64 = *flag;
    int d = (e < N_EDGES) ? edge_at(ei, is64, (long long)N_EDGES + e) : (e - N_EDGES);
    atomicAdd(&counts[d], 1);
}

__global__ void scan_block(const int* in, int* out, int* bsum) {
    __shared__ int sm[256];
    int t = threadIdx.x;
    int i = blockIdx.x * 256 + t;
    int v = (i < N_NODES) ? in[i] : 0;
    int acc = v;
    sm[t] = v; __syncthreads();
    for (int d = 1; d < 256; d <<= 1) {
        int add = (t >= d) ? sm[t - d] : 0;
        __syncthreads();
        acc += add; sm[t] = acc;
        __syncthreads();
    }
    if (i < N_NODES) out[i] = acc - v;   // block-local exclusive
    if (t == 255) bsum[blockIdx.x] = acc;
}

__global__ void scan_bsum(int* bsum, int nb) {
    __shared__ int sm[512];
    int t = threadIdx.x;
    int v = (t < nb) ? bsum[t] : 0;
    int acc = v;
    sm[t] = v; __syncthreads();
    for (int d = 1; d < 512; d <<= 1) {
        int add = (t >= d) ? sm[t - d] : 0;
        __syncthreads();
        acc += add; sm[t] = acc;
        __syncthreads();
    }
    if (t < nb) bsum[t] = acc - v;       // exclusive
}

__global__ void scan_add(int* off, const int* bsum, int* fill) {
    int i = blockIdx.x * 256 + threadIdx.x;
    if (i < N_NODES) {
        int v = off[i] + bsum[blockIdx.x];
        off[i] = v; fill[i] = v;
    }
    if (i == 0) off[N_NODES] = N_TOT;
}

__global__ void scatter_k(const void* ei, const int* flag, int* fill, int* csr_src) {
    int e = blockIdx.x * blockDim.x + threadIdx.x;
    if (e >= N_TOT) return;
    int is64 = *flag;
    int s, d;
    if (e < N_EDGES) { s = edge_at(ei, is64, e); d = edge_at(ei, is64, (long long)N_EDGES + e); }
    else { s = e - N_EDGES; d = s; }
    int pos = atomicAdd(&fill[d], 1);
    csr_src[pos] = s;
}

// ---------------- fp32 GEMM: H[n, 256] = A[n, K] @ W[K, 256] ----------------
__global__ __launch_bounds__(256) void gemm_k(const float* __restrict__ A,
                                              const float* __restrict__ W,
                                              float* __restrict__ H, int K) {
    __shared__ float As[16][68];   // [k][row], padded for alignment
    __shared__ float Ws[16][64];   // [k][col]
    int t = threadIdx.x;
    int bm = blockIdx.x * 64, bn = blockIdx.y * 64;
    int ty = t >> 4, tx = t & 15;
    float acc[4][4] = {{0.f}};
    int ar = t >> 2, ak = (t & 3) * 4;   // A tile load: row, k-offset
    int wr = t >> 4, wc = (t & 15) * 4;  // W tile load: k-row, col

    for (int k0 = 0; k0 < K; k0 += 16) {
        float4 av = make_float4(0.f, 0.f, 0.f, 0.f);
        int grow = bm + ar;
        if (grow < N_NODES) av = *(const float4*)(A + (size_t)grow * K + k0 + ak);
        As[ak][ar] = av.x; As[ak + 1][ar] = av.y; As[ak + 2][ar] = av.z; As[ak + 3][ar] = av.w;
        *(float4*)(&Ws[wr][wc]) = *(const float4*)(W + (size_t)(k0 + wr) * HC + bn + wc);
        __syncthreads();
        #pragma unroll
        for (int kk = 0; kk < 16; ++kk) {
            float4 a  = *(const float4*)(&As[kk][ty * 4]);
            float4 bq = *(const float4*)(&Ws[kk][tx * 4]);
            acc[0][0] += a.x * bq.x; acc[0][1] += a.x * bq.y; acc[0][2] += a.x * bq.z; acc[0][3] += a.x * bq.w;
            acc[1][0] += a.y * bq.x; acc[1][1] += a.y * bq.y; acc[1][2] += a.y * bq.z; acc[1][3] += a.y * bq.w;
            acc[2][0] += a.z * bq.x; acc[2][1] += a.z * bq.y; acc[2][2] += a.z * bq.z; acc[2][3] += a.z * bq.w;
            acc[3][0] += a.w * bq.x; acc[3][1] += a.w * bq.y; acc[3][2] += a.w * bq.z; acc[3][3] += a.w * bq.w;
        }
        __syncthreads();
    }
    #pragma unroll
    for (int r = 0; r < 4; ++r) {
        int grow = bm + ty * 4 + r;
        if (grow < N_NODES)
            *(float4*)(H + (size_t)grow * HC + bn + tx * 4) =
                make_float4(acc[r][0], acc[r][1], acc[r][2], acc[r][3]);
    }
}

// ---------------- per-node attention logits: es/ed [N,4] ----------------
__global__ __launch_bounds__(256) void logits_k(const float* __restrict__ h,
                                                const float* __restrict__ as,
                                                const float* __restrict__ ad,
                                                float* __restrict__ es, float* __restrict__ ed) {
    int wid = (blockIdx.x * blockDim.x + threadIdx.x) >> 6;
    int lane = threadIdx.x & 63;
    if (wid >= N_NODES) return;
    const float* hr = h + (size_t)wid * HC;
    float ps[HEADS], pd[HEADS];
    #pragma unroll
    for (int hh = 0; hh < HEADS; ++hh) {
        float v = hr[hh * CH + lane];
        ps[hh] = v * as[hh * CH + lane];
        pd[hh] = v * ad[hh * CH + lane];
    }
    #pragma unroll
    for (int d = 32; d > 0; d >>= 1) {
        #pragma unroll
        for (int hh = 0; hh < HEADS; ++hh) {
            ps[hh] += __shfl_xor(ps[hh], d);
            pd[hh] += __shfl_xor(pd[hh], d);
        }
    }
    if (lane == 0) {
        *(float4*)(es + (size_t)wid * 4) = make_float4(ps[0], ps[1], ps[2], ps[3]);
        *(float4*)(ed + (size_t)wid * 4) = make_float4(pd[0], pd[1], pd[2], pd[3]);
    }
}

// ---------------- aggregation: softmax over in-edges + weighted sum + BN + ReLU ----------------
__global__ __launch_bounds__(256) void aggregate_k(const float* __restrict__ h,
                                                   const float* __restrict__ es,
                                                   const float* __restrict__ ed,
                                                   const int* __restrict__ off,
                                                   const int* __restrict__ csr,
                                                   const float* __restrict__ bias,
                                                   const float* __restrict__ g,
                                                   const float* __restrict__ bb,
                                                   const float* __restrict__ mu,
                                                   const float* __restrict__ var,
                                                   float* __restrict__ xout) {
    int wid = (blockIdx.x * blockDim.x + threadIdx.x) >> 6;
    int lane = threadIdx.x & 63;
    if (wid >= N_NODES) return;
    int s0 = off[wid], s1 = off[wid + 1];
    float4 edv = *(const float4*)(ed + (size_t)wid * 4);

    // pass 1: per-head max over incoming edges (lane-parallel)
    float m0 = -1e30f, m1 = -1e30f, m2 = -1e30f, m3 = -1e30f;
    for (int e = s0 + lane; e < s1; e += 64) {
        int s = csr[e];
        float4 ev = *(const float4*)(es + (size_t)s * 4);
        m0 = fmaxf(m0, lrelu(ev.x + edv.x));
        m1 = fmaxf(m1, lrelu(ev.y + edv.y));
        m2 = fmaxf(m2, lrelu(ev.z + edv.z));
        m3 = fmaxf(m3, lrelu(ev.w + edv.w));
    }
    #pragma unroll
    for (int d = 32; d > 0; d >>= 1) {
        m0 = fmaxf(m0, __shfl_xor(m0, d));
        m1 = fmaxf(m1, __shfl_xor(m1, d));
        m2 = fmaxf(m2, __shfl_xor(m2, d));
        m3 = fmaxf(m3, __shfl_xor(m3, d));
    }

    // pass 2: serial over edges, lanes cover the 256 features (head = lane>>4)
    int head = lane >> 4;
    float den0 = 0.f, den1 = 0.f, den2 = 0.f, den3 = 0.f;
    float4 acc = make_float4(0.f, 0.f, 0.f, 0.f);
    const float* hl = h + (size_t)lane * 4;
    for (int e = s0; e < s1; ++e) {
        int s = csr[e];
        float4 ev = *(const float4*)(es + (size_t)s * 4);
        float w0 = __expf(lrelu(ev.x + edv.x) - m0);
        float w1 = __expf(lrelu(ev.y + edv.y) - m1);
        float w2 = __expf(lrelu(ev.z + edv.z) - m2);
        float w3 = __expf(lrelu(ev.w + edv.w) - m3);
        den0 += w0; den1 += w1; den2 += w2; den3 += w3;
        float wm = head == 0 ? w0 : head == 1 ? w1 : head == 2 ? w2 : w3;
        float4 hv = *(const float4*)(hl + (size_t)s * HC);
        acc.x += wm * hv.x; acc.y += wm * hv.y; acc.z += wm * hv.z; acc.w += wm * hv.w;
    }
    float den = head == 0 ? den0 : head == 1 ? den1 : head == 2 ? den2 : den3;
    float inv = 1.f / den;
    acc.x *= inv; acc.y *= inv; acc.z *= inv; acc.w *= inv;
    // sum over the 4 heads (lane groups of 16)
    acc.x += __shfl_xor(acc.x, 16); acc.y += __shfl_xor(acc.y, 16);
    acc.z += __shfl_xor(acc.z, 16); acc.w += __shfl_xor(acc.w, 16);
    acc.x += __shfl_xor(acc.x, 32); acc.y += __shfl_xor(acc.y, 32);
    acc.z += __shfl_xor(acc.z, 32); acc.w += __shfl_xor(acc.w, 32);

    if (lane < 16) {
        int c = lane * 4;
        float4 bi = *(const float4*)(bias + c);
        float4 gv = *(const float4*)(g + c);
        float4 bv = *(const float4*)(bb + c);
        float4 mv = *(const float4*)(mu + c);
        float4 vv = *(const float4*)(var + c);
        float o0 = (acc.x * 0.25f + bi.x - mv.x) * (gv.x * rsqrtf(vv.x + BNEPS)) + bv.x;
        float o1 = (acc.y * 0.25f + bi.y - mv.y) * (gv.y * rsqrtf(vv.y + BNEPS)) + bv.y;
        float o2 = (acc.z * 0.25f + bi.z - mv.z) * (gv.z * rsqrtf(vv.z + BNEPS)) + bv.z;
        float o3 = (acc.w * 0.25f + bi.w - mv.w) * (gv.w * rsqrtf(vv.w + BNEPS)) + bv.w;
        *(float4*)(xout + (size_t)wid * CH + c) =
            make_float4(fmaxf(o0, 0.f), fmaxf(o1, 0.f), fmaxf(o2, 0.f), fmaxf(o3, 0.f));
    }
}

// ---------------- MLP head: out = relu(x@W1+b1)@W2+b2 ----------------
__global__ __launch_bounds__(256) void mlp_k(const float* __restrict__ x,
                                             const float* __restrict__ w1,
                                             const float* __restrict__ b1,
                                             const float* __restrict__ w2,
                                             const float* __restrict__ b2,
                                             float* __restrict__ out) {
    __shared__ float w1s[CH * 32];
    __shared__ float w2s[32];
    __shared__ float b1s[32];
    int t = threadIdx.x;
    for (int i = t; i < CH * 32; i += 256) w1s[i] = w1[i];
    if (t < 32) { w2s[t] = w2[t]; b1s[t] = b1[t]; }
    __syncthreads();
    int n = blockIdx.x * 256 + t;
    if (n >= N_NODES) return;
    float y[32];
    #pragma unroll
    for (int j = 0; j < 32; ++j) y[j] = b1s[j];
    const float* xr = x + (size_t)n * CH;
    for (int c4 = 0; c4 < 16; ++c4) {
        float4 xv = *(const float4*)(xr + c4 * 4);
        const float* wr = &w1s[c4 * 4 * 32];
        #pragma unroll
        for (int j = 0; j < 32; ++j)
            y[j] += xv.x * wr[j] + xv.y * wr[32 + j] + xv.z * wr[64 + j] + xv.w * wr[96 + j];
    }
    float o = b2[0];
    #pragma unroll
    for (int j = 0; j < 32; ++j) o += fmaxf(y[j], 0.f) * w2s[j];
    out[n] = o;
}

extern "C" void kernel_launch(void* const* d_in, const int* in_sizes, int n_in,
                              void* d_out, int out_size, void* d_ws, size_t ws_size,
                              hipStream_t stream) {
    const float* x0    = (const float*)d_in[0];
    const void*  ei    = d_in[1];
    const float* W0    = (const float*)d_in[2];
    const float* Wl    = (const float*)d_in[3];
    const float* asrc  = (const float*)d_in[4];
    const float* adst  = (const float*)d_in[5];
    const float* cbias = (const float*)d_in[6];
    const float* bng   = (const float*)d_in[7];
    const float* bnb   = (const float*)d_in[8];
    const float* bnm   = (const float*)d_in[9];
    const float* bnv   = (const float*)d_in[10];
    const float* l1w   = (const float*)d_in[11];
    const float* l1b   = (const float*)d_in[12];
    const float* l2w   = (const float*)d_in[13];
    const float* l2b   = (const float*)d_in[14];
    float* out = (float*)d_out;

    char* p = (char*)d_ws;
    auto alloc = [&](size_t bytes) { char* r = p; p += (bytes + 255) & ~(size_t)255; return r; };
    float* h    = (float*)alloc((size_t)N_NODES * HC * 4);     // 102.4 MB
    float* xA   = (float*)alloc((size_t)N_NODES * CH * 4);     // 25.6 MB
    float* xB   = (float*)alloc((size_t)N_NODES * CH * 4);     // 25.6 MB
    float* es   = (float*)alloc((size_t)N_NODES * 4 * 4);
    float* ed   = (float*)alloc((size_t)N_NODES * 4 * 4);
    int* counts = (int*)alloc((size_t)N_NODES * 4);
    int* off    = (int*)alloc((size_t)(N_NODES + 1) * 4);
    int* fill   = (int*)alloc((size_t)N_NODES * 4);
    int* bsum   = (int*)alloc(512 * 4);
    int* flag   = (int*)alloc(256);
    int* csr    = (int*)alloc((size_t)N_TOT * 4);

    int nbScan = (N_NODES + 255) / 256;   // 391
    hipMemsetAsync(counts, 0, (size_t)N_NODES * 4, stream);
    detect_dtype<<<1, 64, 0, stream>>>((const int*)ei, flag);
    hist_k<<<(N_TOT + 255) / 256, 256, 0, stream>>>(ei, flag, counts);
    scan_block<<<nbScan, 256, 0, stream>>>(counts, off, bsum);
    scan_bsum<<<1, 512, 0, stream>>>(bsum, nbScan);
    scan_add<<<nbScan, 256, 0, stream>>>(off, bsum, fill);
    scatter_k<<<(N_TOT + 255) / 256, 256, 0, stream>>>(ei, flag, fill, csr);

    const float* xin = x0;
    int K = 128;
    const float* W = W0;
    float* xbufs[2] = {xA, xB};
    for (int l = 0; l < 3; ++l) {
        dim3 gg((N_NODES + 63) / 64, HC / 64);
        gemm_k<<<gg, 256, 0, stream>>>(xin, W, h, K);
        logits_k<<<(N_NODES + 3) / 4, 256, 0, stream>>>(h, asrc + l * HC, adst + l * HC, es, ed);
        float* xo = xbufs[l & 1];
        aggregate_k<<<(N_NODES + 3) / 4, 256, 0, stream>>>(h, es, ed, off, csr,
            cbias + l * CH, bng + l * CH, bnb + l * CH, bnm + l * CH, bnv + l * CH, xo);
        xin = xo;
        K = CH;
        W = Wl + (size_t)l * CH * HC;   // next layer uses Wl[l]
    }
    mlp_k<<<(N_NODES + 255) / 256, 256, 0, stream>>>(xin, l1w, l1b, l2w, l2b, out);
}

// Round 2
// 848.909 us; speedup vs baseline: 1.6236x; 1.6236x over previous
//
#include <hip/hip_runtime.h>
#include <hip/hip_bf16.h>
#include <cstdint>

#define N_NODES 100000
#define N_EDGES 1600000
#define N_TOT   1700000   // edges + self loops
#define HEADS   4
#define CH      64
#define HC      256       // HEADS*CH
#define NEG     0.2f
#define BNEPS   1e-5f

static __device__ __forceinline__ float lrelu(float x) {
    return x > 0.f ? x : NEG * x;
}
static __device__ __forceinline__ unsigned short f2bf(float f) {
    unsigned int u = __float_as_uint(f);
    unsigned int r = (u + 0x7fffu + ((u >> 16) & 1u)) >> 16;   // RNE
    return (unsigned short)r;
}
static __device__ __forceinline__ float bflo(unsigned int v) { return __uint_as_float(v << 16); }
static __device__ __forceinline__ float bfhi(unsigned int v) { return __uint_as_float(v & 0xffff0000u); }

// ---------------- edge dtype detection (int32 vs int64) ----------------
__global__ void detect_dtype(const int* ei32, int* flag) {
    int l = threadIdx.x;
    int v = ei32[2 * l + 1];
    unsigned long long b = __ballot(v == 0);
    if (l == 0) *flag = (__popcll(b) >= 48) ? 1 : 0;
}

static __device__ __forceinline__ int edge_at(const void* ei, int is64, long long pos) {
    if (is64) return (int)((const long long*)ei)[pos];
    return ((const int*)ei)[pos];
}

// ---------------- CSR build ----------------
__global__ void hist_k(const void* ei, const int* flag, int* counts) {
    int e = blockIdx.x * blockDim.x + threadIdx.x;
    if (e >= N_TOT) return;
    int is64 = *flag;
    int d = (e < N_EDGES) ? edge_at(ei, is64, (long long)N_EDGES + e) : (e - N_EDGES);
    atomicAdd(&counts[d], 1);
}

__global__ void scan_block(const int* in, int* out, int* bsum) {
    __shared__ int sm[256];
    int t = threadIdx.x;
    int i = blockIdx.x * 256 + t;
    int v = (i < N_NODES) ? in[i] : 0;
    int acc = v;
    sm[t] = v; __syncthreads();
    for (int d = 1; d < 256; d <<= 1) {
        int add = (t >= d) ? sm[t - d] : 0;
        __syncthreads();
        acc += add; sm[t] = acc;
        __syncthreads();
    }
    if (i < N_NODES) out[i] = acc - v;   // block-local exclusive
    if (t == 255) bsum[blockIdx.x] = acc;
}

__global__ void scan_bsum(int* bsum, int nb) {
    __shared__ int sm[512];
    int t = threadIdx.x;
    int v = (t < nb) ? bsum[t] : 0;
    int acc = v;
    sm[t] = v; __syncthreads();
    for (int d = 1; d < 512; d <<= 1) {
        int add = (t >= d) ? sm[t - d] : 0;
        __syncthreads();
        acc += add; sm[t] = acc;
        __syncthreads();
    }
    if (t < nb) bsum[t] = acc - v;       // exclusive
}

__global__ void scan_add(int* off, const int* bsum, int* fill) {
    int i = blockIdx.x * 256 + threadIdx.x;
    if (i < N_NODES) {
        int v = off[i] + bsum[blockIdx.x];
        off[i] = v; fill[i] = v;
    }
    if (i == 0) off[N_NODES] = N_TOT;
}

__global__ void scatter_k(const void* ei, const int* flag, int* fill, int* csr_src) {
    int e = blockIdx.x * blockDim.x + threadIdx.x;
    if (e >= N_TOT) return;
    int is64 = *flag;
    int s, d;
    if (e < N_EDGES) { s = edge_at(ei, is64, e); d = edge_at(ei, is64, (long long)N_EDGES + e); }
    else { s = e - N_EDGES; d = s; }
    int pos = atomicAdd(&fill[d], 1);
    csr_src[pos] = s;
}

// ---- fp32 GEMM H = A@W, fused: write h as bf16 + per-head attention logits ----
// blockIdx.y == head (64 cols == one head exactly)
__global__ __launch_bounds__(256) void gemm_fused_k(const float* __restrict__ A,
                                                    const float* __restrict__ W,
                                                    const float* __restrict__ as,
                                                    const float* __restrict__ ad,
                                                    unsigned short* __restrict__ hb,
                                                    float* __restrict__ es,
                                                    float* __restrict__ ed, int K) {
    __shared__ float As[16][68];   // [k][row]
    __shared__ float Ws[16][64];   // [k][col]
    int t = threadIdx.x;
    int bm = blockIdx.x * 64, bn = blockIdx.y * 64, head = blockIdx.y;
    int ty = t >> 4, tx = t & 15;
    float acc[4][4] = {{0.f}};
    int ar = t >> 2, ak = (t & 3) * 4;
    int wr = t >> 4, wc = (t & 15) * 4;

    for (int k0 = 0; k0 < K; k0 += 16) {
        float4 av = make_float4(0.f, 0.f, 0.f, 0.f);
        int grow = bm + ar;
        if (grow < N_NODES) av = *(const float4*)(A + (size_t)grow * K + k0 + ak);
        As[ak][ar] = av.x; As[ak + 1][ar] = av.y; As[ak + 2][ar] = av.z; As[ak + 3][ar] = av.w;
        *(float4*)(&Ws[wr][wc]) = *(const float4*)(W + (size_t)(k0 + wr) * HC + bn + wc);
        __syncthreads();
        #pragma unroll
        for (int kk = 0; kk < 16; ++kk) {
            float4 a  = *(const float4*)(&As[kk][ty * 4]);
            float4 bq = *(const float4*)(&Ws[kk][tx * 4]);
            acc[0][0] += a.x * bq.x; acc[0][1] += a.x * bq.y; acc[0][2] += a.x * bq.z; acc[0][3] += a.x * bq.w;
            acc[1][0] += a.y * bq.x; acc[1][1] += a.y * bq.y; acc[1][2] += a.y * bq.z; acc[1][3] += a.y * bq.w;
            acc[2][0] += a.z * bq.x; acc[2][1] += a.z * bq.y; acc[2][2] += a.z * bq.z; acc[2][3] += a.z * bq.w;
            acc[3][0] += a.w * bq.x; acc[3][1] += a.w * bq.y; acc[3][2] += a.w * bq.z; acc[3][3] += a.w * bq.w;
        }
        __syncthreads();
    }

    // attention vectors for my 4 columns of this head
    float4 asv = *(const float4*)(as + head * CH + tx * 4);
    float4 adv = *(const float4*)(ad + head * CH + tx * 4);

    #pragma unroll
    for (int r = 0; r < 4; ++r) {
        int grow = bm + ty * 4 + r;
        // bf16 store of h
        if (grow < N_NODES) {
            ushort4 hv;
            hv.x = f2bf(acc[r][0]); hv.y = f2bf(acc[r][1]);
            hv.z = f2bf(acc[r][2]); hv.w = f2bf(acc[r][3]);
            *(ushort4*)(hb + (size_t)grow * HC + bn + tx * 4) = hv;
        }
        // per-head logits (full dot over this block's 64 cols)
        float ps = acc[r][0] * asv.x + acc[r][1] * asv.y + acc[r][2] * asv.z + acc[r][3] * asv.w;
        float pd = acc[r][0] * adv.x + acc[r][1] * adv.y + acc[r][2] * adv.z + acc[r][3] * adv.w;
        #pragma unroll
        for (int d = 1; d < 16; d <<= 1) {
            ps += __shfl_xor(ps, d);
            pd += __shfl_xor(pd, d);
        }
        if (tx == 0 && grow < N_NODES) {
            es[(size_t)grow * 4 + head] = ps;
            ed[(size_t)grow * 4 + head] = pd;
        }
    }
}

// ---- aggregation: edge softmax (no max-shift) + weighted bf16 gather + BN + ReLU ----
__global__ __launch_bounds__(256) void aggregate_k(const unsigned short* __restrict__ h,
                                                   const float* __restrict__ es,
                                                   const float* __restrict__ ed,
                                                   const int* __restrict__ off,
                                                   const int* __restrict__ csr,
                                                   const float* __restrict__ bias,
                                                   const float* __restrict__ g,
                                                   const float* __restrict__ bb,
                                                   const float* __restrict__ mu,
                                                   const float* __restrict__ var,
                                                   float* __restrict__ xout) {
    __shared__ float wbuf[4][64][4];
    __shared__ int   sbuf[4][64];
    int wv = threadIdx.x >> 6;
    int lane = threadIdx.x & 63;
    int wid = blockIdx.x * 4 + wv;
    if (wid >= N_NODES) return;   // no block barriers below -> safe

    int s0 = off[wid], s1 = off[wid + 1];
    float4 edv = *(const float4*)(ed + (size_t)wid * 4);

    int half = lane >> 5;          // which edge of the pair
    int sub  = lane & 31;          // 32 lanes cover one 512B bf16 row
    int head = sub >> 3;           // 8 lanes per head
    float ds0 = 0.f, ds1 = 0.f, ds2 = 0.f, ds3 = 0.f;
    float a0 = 0.f, a1 = 0.f, a2 = 0.f, a3 = 0.f, a4 = 0.f, a5 = 0.f, a6 = 0.f, a7 = 0.f;

    for (int base = s0; base < s1; base += 64) {
        // lane-parallel: per-edge softmax numerators for 64 edges
        int e = base + lane;
        float w0 = 0.f, w1 = 0.f, w2 = 0.f, w3 = 0.f;
        int s = 0;
        if (e < s1) {
            s = csr[e];
            float4 ev = *(const float4*)(es + (size_t)s * 4);
            w0 = __expf(fminf(lrelu(ev.x + edv.x), 80.f));
            w1 = __expf(fminf(lrelu(ev.y + edv.y), 80.f));
            w2 = __expf(fminf(lrelu(ev.z + edv.z), 80.f));
            w3 = __expf(fminf(lrelu(ev.w + edv.w), 80.f));
        }
        ds0 += w0; ds1 += w1; ds2 += w2; ds3 += w3;
        *(float4*)(&wbuf[wv][lane][0]) = make_float4(w0, w1, w2, w3);
        sbuf[wv][lane] = s;
        asm volatile("" ::: "memory");   // keep LDS writes before reads (wave-synchronous)

        int cnt = min(64, s1 - base);
        for (int j = 0; j < cnt; j += 2) {
            int jj = j + half;
            if (jj < cnt) {
                int   ss = sbuf[wv][jj];
                float wm = wbuf[wv][jj][head];
                uint4 hv = *(const uint4*)(h + (size_t)ss * HC + sub * 8);
                a0 = fmaf(wm, bflo(hv.x), a0); a1 = fmaf(wm, bfhi(hv.x), a1);
                a2 = fmaf(wm, bflo(hv.y), a2); a3 = fmaf(wm, bfhi(hv.y), a3);
                a4 = fmaf(wm, bflo(hv.z), a4); a5 = fmaf(wm, bfhi(hv.z), a5);
                a6 = fmaf(wm, bflo(hv.w), a6); a7 = fmaf(wm, bfhi(hv.w), a7);
            }
        }
        asm volatile("" ::: "memory");
    }

    // combine the two edge-parity halves
    a0 += __shfl_xor(a0, 32); a1 += __shfl_xor(a1, 32);
    a2 += __shfl_xor(a2, 32); a3 += __shfl_xor(a3, 32);
    a4 += __shfl_xor(a4, 32); a5 += __shfl_xor(a5, 32);
    a6 += __shfl_xor(a6, 32); a7 += __shfl_xor(a7, 32);

    // full denominators per head
    #pragma unroll
    for (int d = 1; d < 64; d <<= 1) {
        ds0 += __shfl_xor(ds0, d); ds1 += __shfl_xor(ds1, d);
        ds2 += __shfl_xor(ds2, d); ds3 += __shfl_xor(ds3, d);
    }
    float den = head == 0 ? ds0 : head == 1 ? ds1 : head == 2 ? ds2 : ds3;
    float inv = 1.f / den;
    a0 *= inv; a1 *= inv; a2 *= inv; a3 *= inv;
    a4 *= inv; a5 *= inv; a6 *= inv; a7 *= inv;

    // sum the 4 heads (lanes sub, sub^8, sub^16, sub^24)
    a0 += __shfl_xor(a0, 8);  a1 += __shfl_xor(a1, 8);
    a2 += __shfl_xor(a2, 8);  a3 += __shfl_xor(a3, 8);
    a4 += __shfl_xor(a4, 8);  a5 += __shfl_xor(a5, 8);
    a6 += __shfl_xor(a6, 8);  a7 += __shfl_xor(a7, 8);
    a0 += __shfl_xor(a0, 16); a1 += __shfl_xor(a1, 16);
    a2 += __shfl_xor(a2, 16); a3 += __shfl_xor(a3, 16);
    a4 += __shfl_xor(a4, 16); a5 += __shfl_xor(a5, 16);
    a6 += __shfl_xor(a6, 16); a7 += __shfl_xor(a7, 16);

    if (lane < 8) {
        int c = lane * 8;
        float av[8] = {a0, a1, a2, a3, a4, a5, a6, a7};
        float4 bi0 = *(const float4*)(bias + c), bi1 = *(const float4*)(bias + c + 4);
        float4 gv0 = *(const float4*)(g + c),    gv1 = *(const float4*)(g + c + 4);
        float4 bv0 = *(const float4*)(bb + c),   bv1 = *(const float4*)(bb + c + 4);
        float4 mv0 = *(const float4*)(mu + c),   mv1 = *(const float4*)(mu + c + 4);
        float4 vv0 = *(const float4*)(var + c),  vv1 = *(const float4*)(var + c + 4);
        float bia[8] = {bi0.x, bi0.y, bi0.z, bi0.w, bi1.x, bi1.y, bi1.z, bi1.w};
        float gg[8]  = {gv0.x, gv0.y, gv0.z, gv0.w, gv1.x, gv1.y, gv1.z, gv1.w};
        float be[8]  = {bv0.x, bv0.y, bv0.z, bv0.w, bv1.x, bv1.y, bv1.z, bv1.w};
        float mm[8]  = {mv0.x, mv0.y, mv0.z, mv0.w, mv1.x, mv1.y, mv1.z, mv1.w};
        float vv[8]  = {vv0.x, vv0.y, vv0.z, vv0.w, vv1.x, vv1.y, vv1.z, vv1.w};
        float o[8];
        #pragma unroll
        for (int k = 0; k < 8; ++k) {
            float t0 = (av[k] * 0.25f + bia[k] - mm[k]) * (gg[k] * rsqrtf(vv[k] + BNEPS)) + be[k];
            o[k] = fmaxf(t0, 0.f);
        }
        *(float4*)(xout + (size_t)wid * CH + c)     = make_float4(o[0], o[1], o[2], o[3]);
        *(float4*)(xout + (size_t)wid * CH + c + 4) = make_float4(o[4], o[5], o[6], o[7]);
    }
}

// ---------------- MLP head: out = relu(x@W1+b1)@W2+b2 ----------------
__global__ __launch_bounds__(256) void mlp_k(const float* __restrict__ x,
                                             const float* __restrict__ w1,
                                             const float* __restrict__ b1,
                                             const float* __restrict__ w2,
                                             const float* __restrict__ b2,
                                             float* __restrict__ out) {
    __shared__ float w1s[CH * 32];
    __shared__ float w2s[32];
    __shared__ float b1s[32];
    int t = threadIdx.x;
    for (int i = t; i < CH * 32; i += 256) w1s[i] = w1[i];
    if (t < 32) { w2s[t] = w2[t]; b1s[t] = b1[t]; }
    __syncthreads();
    int n = blockIdx.x * 256 + t;
    if (n >= N_NODES) return;
    float y[32];
    #pragma unroll
    for (int j = 0; j < 32; ++j) y[j] = b1s[j];
    const float* xr = x + (size_t)n * CH;
    for (int c4 = 0; c4 < 16; ++c4) {
        float4 xv = *(const float4*)(xr + c4 * 4);
        const float* wr = &w1s[c4 * 4 * 32];
        #pragma unroll
        for (int j = 0; j < 32; ++j)
            y[j] += xv.x * wr[j] + xv.y * wr[32 + j] + xv.z * wr[64 + j] + xv.w * wr[96 + j];
    }
    float o = b2[0];
    #pragma unroll
    for (int j = 0; j < 32; ++j) o += fmaxf(y[j], 0.f) * w2s[j];
    out[n] = o;
}

extern "C" void kernel_launch(void* const* d_in, const int* in_sizes, int n_in,
                              void* d_out, int out_size, void* d_ws, size_t ws_size,
                              hipStream_t stream) {
    const float* x0    = (const float*)d_in[0];
    const void*  ei    = d_in[1];
    const float* W0    = (const float*)d_in[2];
    const float* Wl    = (const float*)d_in[3];
    const float* asrc  = (const float*)d_in[4];
    const float* adst  = (const float*)d_in[5];
    const float* cbias = (const float*)d_in[6];
    const float* bng   = (const float*)d_in[7];
    const float* bnb   = (const float*)d_in[8];
    const float* bnm   = (const float*)d_in[9];
    const float* bnv   = (const float*)d_in[10];
    const float* l1w   = (const float*)d_in[11];
    const float* l1b   = (const float*)d_in[12];
    const float* l2w   = (const float*)d_in[13];
    const float* l2b   = (const float*)d_in[14];
    float* out = (float*)d_out;

    char* p = (char*)d_ws;
    auto alloc = [&](size_t bytes) { char* r = p; p += (bytes + 255) & ~(size_t)255; return r; };
    unsigned short* hb = (unsigned short*)alloc((size_t)N_NODES * HC * 2);  // 51.2 MB bf16
    float* xA   = (float*)alloc((size_t)N_NODES * CH * 4);
    float* xB   = (float*)alloc((size_t)N_NODES * CH * 4);
    float* es   = (float*)alloc((size_t)N_NODES * 4 * 4);
    float* ed   = (float*)alloc((size_t)N_NODES * 4 * 4);
    int* counts = (int*)alloc((size_t)N_NODES * 4);
    int* off    = (int*)alloc((size_t)(N_NODES + 1) * 4);
    int* fill   = (int*)alloc((size_t)N_NODES * 4);
    int* bsum   = (int*)alloc(512 * 4);
    int* flag   = (int*)alloc(256);
    int* csr    = (int*)alloc((size_t)N_TOT * 4);

    int nbScan = (N_NODES + 255) / 256;   // 391
    hipMemsetAsync(counts, 0, (size_t)N_NODES * 4, stream);
    detect_dtype<<<1, 64, 0, stream>>>((const int*)ei, flag);
    hist_k<<<(N_TOT + 255) / 256, 256, 0, stream>>>(ei, flag, counts);
    scan_block<<<nbScan, 256, 0, stream>>>(counts, off, bsum);
    scan_bsum<<<1, 512, 0, stream>>>(bsum, nbScan);
    scan_add<<<nbScan, 256, 0, stream>>>(off, bsum, fill);
    scatter_k<<<(N_TOT + 255) / 256, 256, 0, stream>>>(ei, flag, fill, csr);

    const float* xin = x0;
    int K = 128;
    const float* W = W0;
    float* xbufs[2] = {xA, xB};
    for (int l = 0; l < 3; ++l) {
        dim3 gg((N_NODES + 63) / 64, HC / 64);
        gemm_fused_k<<<gg, 256, 0, stream>>>(xin, W, asrc + l * HC, adst + l * HC,
                                             hb, es, ed, K);
        float* xo = xbufs[l & 1];
        aggregate_k<<<(N_NODES + 3) / 4, 256, 0, stream>>>(hb, es, ed, off, csr,
            cbias + l * CH, bng + l * CH, bnb + l * CH, bnm + l * CH, bnv + l * CH, xo);
        xin = xo;
        K = CH;
        W = Wl + (size_t)l * CH * HC;
    }
    mlp_k<<<(N_NODES + 255) / 256, 256, 0, stream>>>(xin, l1w, l1b, l2w, l2b, out);
}

// Round 3
// 773.650 us; speedup vs baseline: 1.7815x; 1.0973x over previous
//
#include <hip/hip_runtime.h>
#include <hip/hip_bf16.h>
#include <cstdint>

#define N_NODES 100000
#define N_EDGES 1600000
#define N_TOT   1700000   // edges + self loops
#define HEADS   4
#define CH      64
#define HC      256       // HEADS*CH
#define NEG     0.2f
#define BNEPS   1e-5f
#define NPART   8
#define PART_N  12500     // N_NODES / NPART
#define CHUNK_E 16384

typedef __attribute__((ext_vector_type(8))) short short8;
typedef __attribute__((ext_vector_type(4))) float f32x4;

static __device__ __forceinline__ float lrelu(float x) {
    return x > 0.f ? x : NEG * x;
}
static __device__ __forceinline__ unsigned short f2bf(float f) {
    unsigned int u = __float_as_uint(f);
    unsigned int r = (u + 0x7fffu + ((u >> 16) & 1u)) >> 16;   // RNE
    return (unsigned short)r;
}
static __device__ __forceinline__ float bflo(unsigned int v) { return __uint_as_float(v << 16); }
static __device__ __forceinline__ float bfhi(unsigned int v) { return __uint_as_float(v & 0xffff0000u); }

// ---------------- edge dtype detection (int32 vs int64) ----------------
__global__ void detect_dtype(const int* ei32, int* flag) {
    int l = threadIdx.x;
    int v = ei32[2 * l + 1];
    unsigned long long b = __ballot(v == 0);
    if (l == 0) *flag = (__popcll(b) >= 48) ? 1 : 0;
}

static __device__ __forceinline__ int edge_at(const void* ei, int is64, long long pos) {
    if (is64) return (int)((const long long*)ei)[pos];
    return ((const int*)ei)[pos];
}

// convert edge_index (+ self loops) to int32 src/dst
__global__ void convert_k(const void* ei, const int* flag, int* src32, int* dst32) {
    int e = blockIdx.x * 256 + threadIdx.x;
    if (e >= N_TOT) return;
    int is64 = *flag;
    if (e < N_EDGES) {
        src32[e] = edge_at(ei, is64, e);
        dst32[e] = edge_at(ei, is64, (long long)N_EDGES + e);
    } else {
        int v = e - N_EDGES;
        src32[e] = v; dst32[e] = v;
    }
}

// ---------------- CSR build (dst-partitioned for XCD-local L2 writes) ----------------
__global__ void hist_part_k(const int* __restrict__ dst32, int* __restrict__ counts) {
    int part = blockIdx.x & (NPART - 1), chunk = blockIdx.x / NPART;
    int lo = part * PART_N, hi = lo + PART_N;
    int base = chunk * CHUNK_E;
    int end = min(base + CHUNK_E, N_TOT);
    for (int i = base + threadIdx.x; i < end; i += 256) {
        int d = dst32[i];
        if (d >= lo && d < hi) atomicAdd(&counts[d], 1);
    }
}

__global__ void scan_block(const int* in, int* out, int* bsum) {
    __shared__ int sm[256];
    int t = threadIdx.x;
    int i = blockIdx.x * 256 + t;
    int v = (i < N_NODES) ? in[i] : 0;
    int acc = v;
    sm[t] = v; __syncthreads();
    for (int d = 1; d < 256; d <<= 1) {
        int add = (t >= d) ? sm[t - d] : 0;
        __syncthreads();
        acc += add; sm[t] = acc;
        __syncthreads();
    }
    if (i < N_NODES) out[i] = acc - v;
    if (t == 255) bsum[blockIdx.x] = acc;
}

__global__ void scan_bsum(int* bsum, int nb) {
    __shared__ int sm[512];
    int t = threadIdx.x;
    int v = (t < nb) ? bsum[t] : 0;
    int acc = v;
    sm[t] = v; __syncthreads();
    for (int d = 1; d < 512; d <<= 1) {
        int add = (t >= d) ? sm[t - d] : 0;
        __syncthreads();
        acc += add; sm[t] = acc;
        __syncthreads();
    }
    if (t < nb) bsum[t] = acc - v;
}

__global__ void scan_add(int* off, const int* bsum, int* fill) {
    int i = blockIdx.x * 256 + threadIdx.x;
    if (i < N_NODES) {
        int v = off[i] + bsum[blockIdx.x];
        off[i] = v; fill[i] = v;
    }
    if (i == 0) off[N_NODES] = N_TOT;
}

__global__ void scatter_part_k(const int* __restrict__ src32, const int* __restrict__ dst32,
                               int* __restrict__ fill, int* __restrict__ csr) {
    int part = blockIdx.x & (NPART - 1), chunk = blockIdx.x / NPART;
    int lo = part * PART_N, hi = lo + PART_N;
    int base = chunk * CHUNK_E;
    int end = min(base + CHUNK_E, N_TOT);
    for (int i = base + threadIdx.x; i < end; i += 256) {
        int d = dst32[i];
        if (d >= lo && d < hi) {
            int s = src32[i];
            int pos = atomicAdd(&fill[d], 1);
            csr[pos] = s;
        }
    }
}

// ---------------- W fp32 -> bf16 ----------------
__global__ void wconv_k(const float* __restrict__ w, unsigned short* __restrict__ wb, int n) {
    int i = blockIdx.x * 256 + threadIdx.x;
    if (i < n) wb[i] = f2bf(w[i]);
}

// ---- MFMA bf16 GEMM: H[64rows, 256] = A[64, K] @ W[K, 256], fused bf16-h + logits ----
template<int K>
__global__ __launch_bounds__(256) void gemm_mfma_k(const float* __restrict__ A,
                                                   const unsigned short* __restrict__ Wb,
                                                   const float* __restrict__ as,
                                                   const float* __restrict__ ad,
                                                   unsigned short* __restrict__ hb,
                                                   float* __restrict__ es,
                                                   float* __restrict__ ed) {
    __shared__ unsigned short Bs[256 * K];   // [col][k], XOR-swizzled
    __shared__ unsigned short As[64 * K];    // [row][k], XOR-swizzled
    int t = threadIdx.x;
    int bm = blockIdx.x * 64;

    // stage B (bf16 W -> transposed LDS)
    for (int idx4 = t; idx4 < K * 64; idx4 += 256) {
        int k = idx4 >> 6;
        int c = (idx4 & 63) * 4;
        ushort4 wv = *(const ushort4*)(Wb + (size_t)k * HC + c);
        Bs[((c + 0) * K + k) ^ ((((c + 0) & 7)) << 3)] = wv.x;
        Bs[((c + 1) * K + k) ^ ((((c + 1) & 7)) << 3)] = wv.y;
        Bs[((c + 2) * K + k) ^ ((((c + 2) & 7)) << 3)] = wv.z;
        Bs[((c + 3) * K + k) ^ ((((c + 3) & 7)) << 3)] = wv.w;
    }
    // stage A (fp32 -> bf16, row-major)
    {
        int row = t >> 2, seg = t & 3;
        int grow = bm + row;
        const float* Ar = A + (size_t)grow * K + seg * (K / 4);
        #pragma unroll
        for (int f = 0; f < K / 16; ++f) {
            float4 v = make_float4(0.f, 0.f, 0.f, 0.f);
            if (grow < N_NODES) v = *(const float4*)(Ar + f * 4);
            ushort4 b;
            b.x = f2bf(v.x); b.y = f2bf(v.y); b.z = f2bf(v.z); b.w = f2bf(v.w);
            int idx = (row * K + seg * (K / 4) + f * 4) ^ ((row & 7) << 3);
            *(ushort4*)(&As[idx]) = b;
        }
    }
    __syncthreads();

    int w = t >> 6, lane = t & 63;
    int c16 = lane & 15, kg = lane >> 4;
    int swz = (c16 & 7) << 3;
    f32x4 acc[4][4];
    #pragma unroll
    for (int i = 0; i < 4; ++i)
        #pragma unroll
        for (int j = 0; j < 4; ++j) acc[i][j] = (f32x4)(0.f);

    #pragma unroll
    for (int kc = 0; kc < K / 32; ++kc) {
        int ko = kc * 32 + kg * 8;
        short8 af[4], bf[4];
        #pragma unroll
        for (int rs = 0; rs < 4; ++rs)
            af[rs] = *(const short8*)(&As[((16 * rs + c16) * K + ko) ^ swz]);
        #pragma unroll
        for (int ct = 0; ct < 4; ++ct) {
            int col = w * 64 + ct * 16 + c16;
            bf[ct] = *(const short8*)(&Bs[(col * K + ko) ^ swz]);
        }
        #pragma unroll
        for (int rs = 0; rs < 4; ++rs)
            #pragma unroll
            for (int ct = 0; ct < 4; ++ct)
                acc[rs][ct] = __builtin_amdgcn_mfma_f32_16x16x32_bf16(af[rs], bf[ct], acc[rs][ct], 0, 0, 0);
    }

    // epilogue: logits (head w == our 64 cols) + bf16 h store
    float asv[4], adv[4];
    #pragma unroll
    for (int ct = 0; ct < 4; ++ct) {
        asv[ct] = as[w * 64 + ct * 16 + c16];
        adv[ct] = ad[w * 64 + ct * 16 + c16];
    }
    #pragma unroll
    for (int rs = 0; rs < 4; ++rs) {
        float esr[4], edr[4];
        #pragma unroll
        for (int reg = 0; reg < 4; ++reg) {
            float s = 0.f, d = 0.f;
            #pragma unroll
            for (int ct = 0; ct < 4; ++ct) {
                s += acc[rs][ct][reg] * asv[ct];
                d += acc[rs][ct][reg] * adv[ct];
            }
            #pragma unroll
            for (int sh = 1; sh < 16; sh <<= 1) {
                s += __shfl_xor(s, sh);
                d += __shfl_xor(d, sh);
            }
            esr[reg] = s; edr[reg] = d;
        }
        int r0 = bm + rs * 16 + kg * 4;
        if (c16 == 0) {
            #pragma unroll
            for (int reg = 0; reg < 4; ++reg) {
                if (r0 + reg < N_NODES) {
                    es[(size_t)(r0 + reg) * 4 + w] = esr[reg];
                    ed[(size_t)(r0 + reg) * 4 + w] = edr[reg];
                }
            }
        }
        #pragma unroll
        for (int ct = 0; ct < 4; ++ct)
            #pragma unroll
            for (int reg = 0; reg < 4; ++reg) {
                int grow = r0 + reg;
                if (grow < N_NODES)
                    hb[(size_t)grow * HC + w * 64 + ct * 16 + c16] = f2bf(acc[rs][ct][reg]);
            }
    }
}

// ---- aggregation: edge softmax + weighted bf16 gather (4 edges in flight) + BN + ReLU ----
__global__ __launch_bounds__(256) void aggregate_k(const unsigned short* __restrict__ h,
                                                   const float* __restrict__ es,
                                                   const float* __restrict__ ed,
                                                   const int* __restrict__ off,
                                                   const int* __restrict__ csr,
                                                   const float* __restrict__ bias,
                                                   const float* __restrict__ g,
                                                   const float* __restrict__ bb,
                                                   const float* __restrict__ mu,
                                                   const float* __restrict__ var,
                                                   float* __restrict__ xout) {
    __shared__ float wbuf[4][64][4];
    __shared__ int   sbuf[4][64];
    int wv = threadIdx.x >> 6;
    int lane = threadIdx.x & 63;
    int wid = blockIdx.x * 4 + wv;
    if (wid >= N_NODES) return;   // wave-uniform exit, no block barriers below

    int s0 = off[wid], s1 = off[wid + 1];
    float4 edv = *(const float4*)(ed + (size_t)wid * 4);

    int q = lane >> 4;            // edge slot within group of 4
    int s16 = lane & 15;          // 16 lanes cover one 512B bf16 row (32B each)
    int head = s16 >> 2;
    float ds0 = 0.f, ds1 = 0.f, ds2 = 0.f, ds3 = 0.f;
    float a[16];
    #pragma unroll
    for (int i = 0; i < 16; ++i) a[i] = 0.f;

    for (int base = s0; base < s1; base += 64) {
        // phase 1 (lane = edge): softmax numerators for up to 64 edges
        int e = base + lane;
        float w0 = 0.f, w1 = 0.f, w2 = 0.f, w3 = 0.f;
        int s = 0;
        if (e < s1) {
            s = csr[e];
            float4 ev = *(const float4*)(es + (size_t)s * 4);
            w0 = __expf(fminf(lrelu(ev.x + edv.x), 80.f));
            w1 = __expf(fminf(lrelu(ev.y + edv.y), 80.f));
            w2 = __expf(fminf(lrelu(ev.z + edv.z), 80.f));
            w3 = __expf(fminf(lrelu(ev.w + edv.w), 80.f));
        }
        ds0 += w0; ds1 += w1; ds2 += w2; ds3 += w3;
        *(float4*)(&wbuf[wv][lane][0]) = make_float4(w0, w1, w2, w3);
        sbuf[wv][lane] = s;
        asm volatile("" ::: "memory");   // wave-synchronous LDS ordering

        // phase 2: 4 edges in flight, 16 lanes x 32B per row
        int cnt = min(64, s1 - base);
        for (int j = 0; j < cnt; j += 4) {
            int jj = j + q;
            if (jj < cnt) {
                int   ss = sbuf[wv][jj];
                float wm = wbuf[wv][jj][head];
                const unsigned short* hp = h + (size_t)ss * HC + s16 * 16;
                uint4 h0 = *(const uint4*)hp;
                uint4 h1 = *(const uint4*)(hp + 8);
                a[0]  = fmaf(wm, bflo(h0.x), a[0]);  a[1]  = fmaf(wm, bfhi(h0.x), a[1]);
                a[2]  = fmaf(wm, bflo(h0.y), a[2]);  a[3]  = fmaf(wm, bfhi(h0.y), a[3]);
                a[4]  = fmaf(wm, bflo(h0.z), a[4]);  a[5]  = fmaf(wm, bfhi(h0.z), a[5]);
                a[6]  = fmaf(wm, bflo(h0.w), a[6]);  a[7]  = fmaf(wm, bfhi(h0.w), a[7]);
                a[8]  = fmaf(wm, bflo(h1.x), a[8]);  a[9]  = fmaf(wm, bfhi(h1.x), a[9]);
                a[10] = fmaf(wm, bflo(h1.y), a[10]); a[11] = fmaf(wm, bfhi(h1.y), a[11]);
                a[12] = fmaf(wm, bflo(h1.z), a[12]); a[13] = fmaf(wm, bfhi(h1.z), a[13]);
                a[14] = fmaf(wm, bflo(h1.w), a[14]); a[15] = fmaf(wm, bfhi(h1.w), a[15]);
            }
        }
        asm volatile("" ::: "memory");
    }

    // combine the 4 edge slots
    #pragma unroll
    for (int i = 0; i < 16; ++i) {
        a[i] += __shfl_xor(a[i], 16);
        a[i] += __shfl_xor(a[i], 32);
    }
    // full per-head denominators
    #pragma unroll
    for (int d = 1; d < 64; d <<= 1) {
        ds0 += __shfl_xor(ds0, d); ds1 += __shfl_xor(ds1, d);
        ds2 += __shfl_xor(ds2, d); ds3 += __shfl_xor(ds3, d);
    }
    float den = head == 0 ? ds0 : head == 1 ? ds1 : head == 2 ? ds2 : ds3;
    float inv = 1.f / den;
    #pragma unroll
    for (int i = 0; i < 16; ++i) a[i] *= inv;
    // head mean: lanes s16, s16^4, s16^8, s16^12 hold the 4 heads
    #pragma unroll
    for (int i = 0; i < 16; ++i) {
        a[i] += __shfl_xor(a[i], 4);
        a[i] += __shfl_xor(a[i], 8);
    }

    if (lane < 4) {
        int c0 = lane * 16;
        float o[16];
        #pragma unroll
        for (int v4 = 0; v4 < 4; ++v4) {
            int c = c0 + v4 * 4;
            float4 bi = *(const float4*)(bias + c);
            float4 gv = *(const float4*)(g + c);
            float4 bv = *(const float4*)(bb + c);
            float4 mv = *(const float4*)(mu + c);
            float4 vv = *(const float4*)(var + c);
            o[v4 * 4 + 0] = fmaxf((a[v4 * 4 + 0] * 0.25f + bi.x - mv.x) * (gv.x * rsqrtf(vv.x + BNEPS)) + bv.x, 0.f);
            o[v4 * 4 + 1] = fmaxf((a[v4 * 4 + 1] * 0.25f + bi.y - mv.y) * (gv.y * rsqrtf(vv.y + BNEPS)) + bv.y, 0.f);
            o[v4 * 4 + 2] = fmaxf((a[v4 * 4 + 2] * 0.25f + bi.z - mv.z) * (gv.z * rsqrtf(vv.z + BNEPS)) + bv.z, 0.f);
            o[v4 * 4 + 3] = fmaxf((a[v4 * 4 + 3] * 0.25f + bi.w - mv.w) * (gv.w * rsqrtf(vv.w + BNEPS)) + bv.w, 0.f);
        }
        #pragma unroll
        for (int v4 = 0; v4 < 4; ++v4)
            *(float4*)(xout + (size_t)wid * CH + c0 + v4 * 4) =
                make_float4(o[v4 * 4 + 0], o[v4 * 4 + 1], o[v4 * 4 + 2], o[v4 * 4 + 3]);
    }
}

// ---------------- MLP head: out = relu(x@W1+b1)@W2+b2 ----------------
__global__ __launch_bounds__(256) void mlp_k(const float* __restrict__ x,
                                             const float* __restrict__ w1,
                                             const float* __restrict__ b1,
                                             const float* __restrict__ w2,
                                             const float* __restrict__ b2,
                                             float* __restrict__ out) {
    __shared__ float w1s[CH * 32];
    __shared__ float w2s[32];
    __shared__ float b1s[32];
    int t = threadIdx.x;
    for (int i = t; i < CH * 32; i += 256) w1s[i] = w1[i];
    if (t < 32) { w2s[t] = w2[t]; b1s[t] = b1[t]; }
    __syncthreads();
    int n = blockIdx.x * 256 + t;
    if (n >= N_NODES) return;
    float y[32];
    #pragma unroll
    for (int j = 0; j < 32; ++j) y[j] = b1s[j];
    const float* xr = x + (size_t)n * CH;
    for (int c4 = 0; c4 < 16; ++c4) {
        float4 xv = *(const float4*)(xr + c4 * 4);
        const float* wr = &w1s[c4 * 4 * 32];
        #pragma unroll
        for (int j = 0; j < 32; ++j)
            y[j] += xv.x * wr[j] + xv.y * wr[32 + j] + xv.z * wr[64 + j] + xv.w * wr[96 + j];
    }
    float o = b2[0];
    #pragma unroll
    for (int j = 0; j < 32; ++j) o += fmaxf(y[j], 0.f) * w2s[j];
    out[n] = o;
}

extern "C" void kernel_launch(void* const* d_in, const int* in_sizes, int n_in,
                              void* d_out, int out_size, void* d_ws, size_t ws_size,
                              hipStream_t stream) {
    const float* x0    = (const float*)d_in[0];
    const void*  ei    = d_in[1];
    const float* W0    = (const float*)d_in[2];
    const float* Wl    = (const float*)d_in[3];
    const float* asrc  = (const float*)d_in[4];
    const float* adst  = (const float*)d_in[5];
    const float* cbias = (const float*)d_in[6];
    const float* bng   = (const float*)d_in[7];
    const float* bnb   = (const float*)d_in[8];
    const float* bnm   = (const float*)d_in[9];
    const float* bnv   = (const float*)d_in[10];
    const float* l1w   = (const float*)d_in[11];
    const float* l1b   = (const float*)d_in[12];
    const float* l2w   = (const float*)d_in[13];
    const float* l2b   = (const float*)d_in[14];
    float* out = (float*)d_out;

    char* p = (char*)d_ws;
    auto alloc = [&](size_t bytes) { char* r = p; p += (bytes + 255) & ~(size_t)255; return r; };
    unsigned short* hb  = (unsigned short*)alloc((size_t)N_NODES * HC * 2);  // 51.2 MB
    unsigned short* wbf = (unsigned short*)alloc((size_t)128 * HC * 2);      // 64 KB
    float* xA   = (float*)alloc((size_t)N_NODES * CH * 4);
    float* xB   = (float*)alloc((size_t)N_NODES * CH * 4);
    float* es   = (float*)alloc((size_t)N_NODES * 4 * 4);
    float* ed   = (float*)alloc((size_t)N_NODES * 4 * 4);
    int* counts = (int*)alloc((size_t)N_NODES * 4);
    int* off    = (int*)alloc((size_t)(N_NODES + 1) * 4);
    int* fill   = (int*)alloc((size_t)N_NODES * 4);
    int* bsum   = (int*)alloc(512 * 4);
    int* flag   = (int*)alloc(256);
    int* src32  = (int*)alloc((size_t)N_TOT * 4);
    int* dst32  = (int*)alloc((size_t)N_TOT * 4);
    int* csr    = (int*)alloc((size_t)N_TOT * 4);

    int nbScan = (N_NODES + 255) / 256;   // 391
    int nchunk = (N_TOT + CHUNK_E - 1) / CHUNK_E;   // 104
    hipMemsetAsync(counts, 0, (size_t)N_NODES * 4, stream);
    detect_dtype<<<1, 64, 0, stream>>>((const int*)ei, flag);
    convert_k<<<(N_TOT + 255) / 256, 256, 0, stream>>>(ei, flag, src32, dst32);
    hist_part_k<<<nchunk * NPART, 256, 0, stream>>>(dst32, counts);
    scan_block<<<nbScan, 256, 0, stream>>>(counts, off, bsum);
    scan_bsum<<<1, 512, 0, stream>>>(bsum, nbScan);
    scan_add<<<nbScan, 256, 0, stream>>>(off, bsum, fill);
    scatter_part_k<<<nchunk * NPART, 256, 0, stream>>>(src32, dst32, fill, csr);

    const float* xin = x0;
    const float* W = W0;
    float* xbufs[2] = {xA, xB};
    int ngemm = (N_NODES + 63) / 64;
    for (int l = 0; l < 3; ++l) {
        int K = (l == 0) ? 128 : 64;
        wconv_k<<<(K * HC + 255) / 256, 256, 0, stream>>>(W, wbf, K * HC);
        if (l == 0)
            gemm_mfma_k<128><<<ngemm, 256, 0, stream>>>(xin, wbf, asrc + l * HC, adst + l * HC, hb, es, ed);
        else
            gemm_mfma_k<64><<<ngemm, 256, 0, stream>>>(xin, wbf, asrc + l * HC, adst + l * HC, hb, es, ed);
        float* xo = xbufs[l & 1];
        aggregate_k<<<(N_NODES + 3) / 4, 256, 0, stream>>>(hb, es, ed, off, csr,
            cbias + l * CH, bng + l * CH, bnb + l * CH, bnm + l * CH, bnv + l * CH, xo);
        xin = xo;
        W = Wl + (size_t)l * CH * HC;
    }
    mlp_k<<<(N_NODES + 255) / 256, 256, 0, stream>>>(xin, l1w, l1b, l2w, l2b, out);
}

// Round 4
// 747.354 us; speedup vs baseline: 1.8442x; 1.0352x over previous
//
#include <hip/hip_runtime.h>
#include <hip/hip_bf16.h>
#include <cstdint>

#define N_NODES 100000
#define N_EDGES 1600000
#define N_TOT   1700000   // edges + self loops
#define HEADS   4
#define CH      64
#define HC      256       // HEADS*CH
#define NEG     0.2f
#define BNEPS   1e-5f
#define NPART   8
#define PART_N  12500     // N_NODES / NPART
#define CHUNK_E 16384

typedef __attribute__((ext_vector_type(8))) short short8;
typedef __attribute__((ext_vector_type(4))) float f32x4;

static __device__ __forceinline__ float lrelu(float x) {
    return x > 0.f ? x : NEG * x;
}
static __device__ __forceinline__ unsigned short f2bf(float f) {
    unsigned int u = __float_as_uint(f);
    unsigned int r = (u + 0x7fffu + ((u >> 16) & 1u)) >> 16;   // RNE
    return (unsigned short)r;
}
static __device__ __forceinline__ float bflo(unsigned int v) { return __uint_as_float(v << 16); }
static __device__ __forceinline__ float bfhi(unsigned int v) { return __uint_as_float(v & 0xffff0000u); }

// ---------------- edge dtype detection (int32 vs int64) ----------------
__global__ void detect_dtype(const int* ei32, int* flag) {
    int l = threadIdx.x;
    int v = ei32[2 * l + 1];
    unsigned long long b = __ballot(v == 0);
    if (l == 0) *flag = (__popcll(b) >= 48) ? 1 : 0;
}

static __device__ __forceinline__ int edge_at(const void* ei, int is64, long long pos) {
    if (is64) return (int)((const long long*)ei)[pos];
    return ((const int*)ei)[pos];
}

// ---------------- fused convert + histogram (one pass over edge_index) ----------------
__global__ void convert_hist_k(const void* ei, const int* flag,
                               int* __restrict__ src32, int* __restrict__ dst32,
                               int* __restrict__ counts) {
    int e = blockIdx.x * 256 + threadIdx.x;
    if (e >= N_TOT) return;
    int is64 = *flag;
    int s, d;
    if (e < N_EDGES) { s = edge_at(ei, is64, e); d = edge_at(ei, is64, (long long)N_EDGES + e); }
    else { int v = e - N_EDGES; s = v; d = v; }
    src32[e] = s; dst32[e] = d;
    atomicAdd(&counts[d], 1);
}

__global__ void scan_block(const int* in, int* out, int* bsum) {
    __shared__ int sm[256];
    int t = threadIdx.x;
    int i = blockIdx.x * 256 + t;
    int v = (i < N_NODES) ? in[i] : 0;
    int acc = v;
    sm[t] = v; __syncthreads();
    for (int d = 1; d < 256; d <<= 1) {
        int add = (t >= d) ? sm[t - d] : 0;
        __syncthreads();
        acc += add; sm[t] = acc;
        __syncthreads();
    }
    if (i < N_NODES) out[i] = acc - v;
    if (t == 255) bsum[blockIdx.x] = acc;
}

__global__ void scan_bsum(int* bsum, int nb) {
    __shared__ int sm[512];
    int t = threadIdx.x;
    int v = (t < nb) ? bsum[t] : 0;
    int acc = v;
    sm[t] = v; __syncthreads();
    for (int d = 1; d < 512; d <<= 1) {
        int add = (t >= d) ? sm[t - d] : 0;
        __syncthreads();
        acc += add; sm[t] = acc;
        __syncthreads();
    }
    if (t < nb) bsum[t] = acc - v;
}

__global__ void scan_add(int* off, const int* bsum, int* fill) {
    int i = blockIdx.x * 256 + threadIdx.x;
    if (i < N_NODES) {
        int v = off[i] + bsum[blockIdx.x];
        off[i] = v; fill[i] = v;
    }
    if (i == 0) off[N_NODES] = N_TOT;
}

// dst-partitioned scatter: each partition's csr range is written by one XCD's blocks
__global__ void scatter_part_k(const int* __restrict__ src32, const int* __restrict__ dst32,
                               int* __restrict__ fill, int* __restrict__ csr) {
    int part = blockIdx.x & (NPART - 1), chunk = blockIdx.x / NPART;
    int lo = part * PART_N, hi = lo + PART_N;
    int base = chunk * CHUNK_E;
    int end = min(base + CHUNK_E, N_TOT);
    for (int i = base + threadIdx.x; i < end; i += 256) {
        int d = dst32[i];
        if (d >= lo && d < hi) {
            int s = src32[i];
            int pos = atomicAdd(&fill[d], 1);
            csr[pos] = s;
        }
    }
}

// ---- MFMA bf16 GEMM: H[64rows, 256] = A[64, K] @ W[K, 256], fused bf16-h + logits ----
// W read as fp32 and converted during LDS staging (L2-resident, no separate pass)
template<int K>
__global__ __launch_bounds__(256) void gemm_mfma_k(const float* __restrict__ A,
                                                   const float* __restrict__ Wf,
                                                   const float* __restrict__ as,
                                                   const float* __restrict__ ad,
                                                   unsigned short* __restrict__ hb,
                                                   float* __restrict__ es,
                                                   float* __restrict__ ed) {
    __shared__ unsigned short Bs[256 * K];   // [col][k], XOR-swizzled
    __shared__ unsigned short As[64 * K];    // [row][k], XOR-swizzled
    int t = threadIdx.x;
    int bm = blockIdx.x * 64;

    // stage B (fp32 W -> bf16 transposed LDS)
    for (int idx4 = t; idx4 < K * 64; idx4 += 256) {
        int k = idx4 >> 6;
        int c = (idx4 & 63) * 4;
        float4 wv = *(const float4*)(Wf + (size_t)k * HC + c);
        Bs[((c + 0) * K + k) ^ ((((c + 0) & 7)) << 3)] = f2bf(wv.x);
        Bs[((c + 1) * K + k) ^ ((((c + 1) & 7)) << 3)] = f2bf(wv.y);
        Bs[((c + 2) * K + k) ^ ((((c + 2) & 7)) << 3)] = f2bf(wv.z);
        Bs[((c + 3) * K + k) ^ ((((c + 3) & 7)) << 3)] = f2bf(wv.w);
    }
    // stage A (fp32 -> bf16, row-major)
    {
        int row = t >> 2, seg = t & 3;
        int grow = bm + row;
        const float* Ar = A + (size_t)grow * K + seg * (K / 4);
        #pragma unroll
        for (int f = 0; f < K / 16; ++f) {
            float4 v = make_float4(0.f, 0.f, 0.f, 0.f);
            if (grow < N_NODES) v = *(const float4*)(Ar + f * 4);
            ushort4 b;
            b.x = f2bf(v.x); b.y = f2bf(v.y); b.z = f2bf(v.z); b.w = f2bf(v.w);
            int idx = (row * K + seg * (K / 4) + f * 4) ^ ((row & 7) << 3);
            *(ushort4*)(&As[idx]) = b;
        }
    }
    __syncthreads();

    int w = t >> 6, lane = t & 63;
    int c16 = lane & 15, kg = lane >> 4;
    int swz = (c16 & 7) << 3;
    f32x4 acc[4][4];
    #pragma unroll
    for (int i = 0; i < 4; ++i)
        #pragma unroll
        for (int j = 0; j < 4; ++j) acc[i][j] = (f32x4)(0.f);

    #pragma unroll
    for (int kc = 0; kc < K / 32; ++kc) {
        int ko = kc * 32 + kg * 8;
        short8 af[4], bf[4];
        #pragma unroll
        for (int rs = 0; rs < 4; ++rs)
            af[rs] = *(const short8*)(&As[((16 * rs + c16) * K + ko) ^ swz]);
        #pragma unroll
        for (int ct = 0; ct < 4; ++ct) {
            int col = w * 64 + ct * 16 + c16;
            bf[ct] = *(const short8*)(&Bs[(col * K + ko) ^ swz]);
        }
        #pragma unroll
        for (int rs = 0; rs < 4; ++rs)
            #pragma unroll
            for (int ct = 0; ct < 4; ++ct)
                acc[rs][ct] = __builtin_amdgcn_mfma_f32_16x16x32_bf16(af[rs], bf[ct], acc[rs][ct], 0, 0, 0);
    }

    // epilogue: logits (head w == our 64 cols) + bf16 h store
    float asv[4], adv[4];
    #pragma unroll
    for (int ct = 0; ct < 4; ++ct) {
        asv[ct] = as[w * 64 + ct * 16 + c16];
        adv[ct] = ad[w * 64 + ct * 16 + c16];
    }
    #pragma unroll
    for (int rs = 0; rs < 4; ++rs) {
        float esr[4], edr[4];
        #pragma unroll
        for (int reg = 0; reg < 4; ++reg) {
            float s = 0.f, d = 0.f;
            #pragma unroll
            for (int ct = 0; ct < 4; ++ct) {
                s += acc[rs][ct][reg] * asv[ct];
                d += acc[rs][ct][reg] * adv[ct];
            }
            #pragma unroll
            for (int sh = 1; sh < 16; sh <<= 1) {
                s += __shfl_xor(s, sh);
                d += __shfl_xor(d, sh);
            }
            esr[reg] = s; edr[reg] = d;
        }
        int r0 = bm + rs * 16 + kg * 4;
        if (c16 == 0) {
            #pragma unroll
            for (int reg = 0; reg < 4; ++reg) {
                if (r0 + reg < N_NODES) {
                    es[(size_t)(r0 + reg) * 4 + w] = esr[reg];
                    ed[(size_t)(r0 + reg) * 4 + w] = edr[reg];
                }
            }
        }
        #pragma unroll
        for (int ct = 0; ct < 4; ++ct)
            #pragma unroll
            for (int reg = 0; reg < 4; ++reg) {
                int grow = r0 + reg;
                if (grow < N_NODES)
                    hb[(size_t)grow * HC + w * 64 + ct * 16 + c16] = f2bf(acc[rs][ct][reg]);
            }
    }
}

// ---- aggregation: edge softmax + weighted bf16 gather (depth-2 pipelined) + BN + ReLU ----
__global__ __launch_bounds__(256) void aggregate_k(const unsigned short* __restrict__ h,
                                                   const float* __restrict__ es,
                                                   const float* __restrict__ ed,
                                                   const int* __restrict__ off,
                                                   const int* __restrict__ csr,
                                                   const float* __restrict__ bias,
                                                   const float* __restrict__ g,
                                                   const float* __restrict__ bb,
                                                   const float* __restrict__ mu,
                                                   const float* __restrict__ var,
                                                   float* __restrict__ xout) {
    __shared__ float wbuf[4][64][4];
    __shared__ int   sbuf[4][64];
    int wv = threadIdx.x >> 6;
    int lane = threadIdx.x & 63;
    int wid = blockIdx.x * 4 + wv;
    if (wid >= N_NODES) return;   // wave-uniform exit, no block barriers below

    int s0 = off[wid], s1 = off[wid + 1];
    float4 edv = *(const float4*)(ed + (size_t)wid * 4);

    int half = lane >> 5;          // which edge of the pair
    int sub  = lane & 31;          // 32 lanes cover one 512B bf16 row
    int head = sub >> 3;           // 8 lanes per head
    float ds0 = 0.f, ds1 = 0.f, ds2 = 0.f, ds3 = 0.f;
    float a0 = 0.f, a1 = 0.f, a2 = 0.f, a3 = 0.f, a4 = 0.f, a5 = 0.f, a6 = 0.f, a7 = 0.f;
    const unsigned short* hsub = h + sub * 8;

    for (int base = s0; base < s1; base += 64) {
        // phase 1 (lane = edge): softmax numerators for up to 64 edges
        int e = base + lane;
        float w0 = 0.f, w1 = 0.f, w2 = 0.f, w3 = 0.f;
        int s = 0;
        if (e < s1) {
            s = csr[e];
            float4 ev = *(const float4*)(es + (size_t)s * 4);
            w0 = __expf(fminf(lrelu(ev.x + edv.x), 80.f));
            w1 = __expf(fminf(lrelu(ev.y + edv.y), 80.f));
            w2 = __expf(fminf(lrelu(ev.z + edv.z), 80.f));
            w3 = __expf(fminf(lrelu(ev.w + edv.w), 80.f));
        }
        ds0 += w0; ds1 += w1; ds2 += w2; ds3 += w3;
        *(float4*)(&wbuf[wv][lane][0]) = make_float4(w0, w1, w2, w3);
        sbuf[wv][lane] = s;
        asm volatile("" ::: "memory");   // wave-synchronous LDS ordering

        // phase 2: 2 edges per iteration (32 lanes x 16B per row), depth-2 pipeline
        int cnt = min(64, s1 - base);
        int jj = half;
        int scur = (jj < cnt) ? sbuf[wv][jj] : sbuf[wv][0];
        float wcur = (jj < cnt) ? wbuf[wv][jj][head] : 0.f;
        uint4 hv = *(const uint4*)(hsub + (size_t)scur * HC);
        for (int j = 0; j < cnt; j += 2) {
            int jn = j + 2 + half;
            int snx = (jn < cnt) ? sbuf[wv][jn] : sbuf[wv][0];
            float wnx = (jn < cnt) ? wbuf[wv][jn][head] : 0.f;
            uint4 hn = *(const uint4*)(hsub + (size_t)snx * HC);   // prefetch next pair
            a0 = fmaf(wcur, bflo(hv.x), a0); a1 = fmaf(wcur, bfhi(hv.x), a1);
            a2 = fmaf(wcur, bflo(hv.y), a2); a3 = fmaf(wcur, bfhi(hv.y), a3);
            a4 = fmaf(wcur, bflo(hv.z), a4); a5 = fmaf(wcur, bfhi(hv.z), a5);
            a6 = fmaf(wcur, bflo(hv.w), a6); a7 = fmaf(wcur, bfhi(hv.w), a7);
            hv = hn; wcur = wnx;
        }
        asm volatile("" ::: "memory");
    }

    // combine the two edge-parity halves
    a0 += __shfl_xor(a0, 32); a1 += __shfl_xor(a1, 32);
    a2 += __shfl_xor(a2, 32); a3 += __shfl_xor(a3, 32);
    a4 += __shfl_xor(a4, 32); a5 += __shfl_xor(a5, 32);
    a6 += __shfl_xor(a6, 32); a7 += __shfl_xor(a7, 32);

    // full denominators per head
    #pragma unroll
    for (int d = 1; d < 64; d <<= 1) {
        ds0 += __shfl_xor(ds0, d); ds1 += __shfl_xor(ds1, d);
        ds2 += __shfl_xor(ds2, d); ds3 += __shfl_xor(ds3, d);
    }
    float den = head == 0 ? ds0 : head == 1 ? ds1 : head == 2 ? ds2 : ds3;
    float inv = 1.f / den;
    a0 *= inv; a1 *= inv; a2 *= inv; a3 *= inv;
    a4 *= inv; a5 *= inv; a6 *= inv; a7 *= inv;

    // sum the 4 heads (lanes sub, sub^8, sub^16, sub^24)
    a0 += __shfl_xor(a0, 8);  a1 += __shfl_xor(a1, 8);
    a2 += __shfl_xor(a2, 8);  a3 += __shfl_xor(a3, 8);
    a4 += __shfl_xor(a4, 8);  a5 += __shfl_xor(a5, 8);
    a6 += __shfl_xor(a6, 8);  a7 += __shfl_xor(a7, 8);
    a0 += __shfl_xor(a0, 16); a1 += __shfl_xor(a1, 16);
    a2 += __shfl_xor(a2, 16); a3 += __shfl_xor(a3, 16);
    a4 += __shfl_xor(a4, 16); a5 += __shfl_xor(a5, 16);
    a6 += __shfl_xor(a6, 16); a7 += __shfl_xor(a7, 16);

    if (lane < 8) {
        int c = lane * 8;
        float av[8] = {a0, a1, a2, a3, a4, a5, a6, a7};
        float4 bi0 = *(const float4*)(bias + c), bi1 = *(const float4*)(bias + c + 4);
        float4 gv0 = *(const float4*)(g + c),    gv1 = *(const float4*)(g + c + 4);
        float4 bv0 = *(const float4*)(bb + c),   bv1 = *(const float4*)(bb + c + 4);
        float4 mv0 = *(const float4*)(mu + c),   mv1 = *(const float4*)(mu + c + 4);
        float4 vv0 = *(const float4*)(var + c),  vv1 = *(const float4*)(var + c + 4);
        float bia[8] = {bi0.x, bi0.y, bi0.z, bi0.w, bi1.x, bi1.y, bi1.z, bi1.w};
        float gg[8]  = {gv0.x, gv0.y, gv0.z, gv0.w, gv1.x, gv1.y, gv1.z, gv1.w};
        float be[8]  = {bv0.x, bv0.y, bv0.z, bv0.w, bv1.x, bv1.y, bv1.z, bv1.w};
        float mm[8]  = {mv0.x, mv0.y, mv0.z, mv0.w, mv1.x, mv1.y, mv1.z, mv1.w};
        float vv[8]  = {vv0.x, vv0.y, vv0.z, vv0.w, vv1.x, vv1.y, vv1.z, vv1.w};
        float o[8];
        #pragma unroll
        for (int k = 0; k < 8; ++k) {
            float t0 = (av[k] * 0.25f + bia[k] - mm[k]) * (gg[k] * rsqrtf(vv[k] + BNEPS)) + be[k];
            o[k] = fmaxf(t0, 0.f);
        }
        *(float4*)(xout + (size_t)wid * CH + c)     = make_float4(o[0], o[1], o[2], o[3]);
        *(float4*)(xout + (size_t)wid * CH + c + 4) = make_float4(o[4], o[5], o[6], o[7]);
    }
}

// ---------------- MLP head: out = relu(x@W1+b1)@W2+b2 ----------------
__global__ __launch_bounds__(256) void mlp_k(const float* __restrict__ x,
                                             const float* __restrict__ w1,
                                             const float* __restrict__ b1,
                                             const float* __restrict__ w2,
                                             const float* __restrict__ b2,
                                             float* __restrict__ out) {
    __shared__ float w1s[CH * 32];
    __shared__ float w2s[32];
    __shared__ float b1s[32];
    int t = threadIdx.x;
    for (int i = t; i < CH * 32; i += 256) w1s[i] = w1[i];
    if (t < 32) { w2s[t] = w2[t]; b1s[t] = b1[t]; }
    __syncthreads();
    int n = blockIdx.x * 256 + t;
    if (n >= N_NODES) return;
    float y[32];
    #pragma unroll
    for (int j = 0; j < 32; ++j) y[j] = b1s[j];
    const float* xr = x + (size_t)n * CH;
    for (int c4 = 0; c4 < 16; ++c4) {
        float4 xv = *(const float4*)(xr + c4 * 4);
        const float* wr = &w1s[c4 * 4 * 32];
        #pragma unroll
        for (int j = 0; j < 32; ++j)
            y[j] += xv.x * wr[j] + xv.y * wr[32 + j] + xv.z * wr[64 + j] + xv.w * wr[96 + j];
    }
    float o = b2[0];
    #pragma unroll
    for (int j = 0; j < 32; ++j) o += fmaxf(y[j], 0.f) * w2s[j];
    out[n] = o;
}

extern "C" void kernel_launch(void* const* d_in, const int* in_sizes, int n_in,
                              void* d_out, int out_size, void* d_ws, size_t ws_size,
                              hipStream_t stream) {
    const float* x0    = (const float*)d_in[0];
    const void*  ei    = d_in[1];
    const float* W0    = (const float*)d_in[2];
    const float* Wl    = (const float*)d_in[3];
    const float* asrc  = (const float*)d_in[4];
    const float* adst  = (const float*)d_in[5];
    const float* cbias = (const float*)d_in[6];
    const float* bng   = (const float*)d_in[7];
    const float* bnb   = (const float*)d_in[8];
    const float* bnm   = (const float*)d_in[9];
    const float* bnv   = (const float*)d_in[10];
    const float* l1w   = (const float*)d_in[11];
    const float* l1b   = (const float*)d_in[12];
    const float* l2w   = (const float*)d_in[13];
    const float* l2b   = (const float*)d_in[14];
    float* out = (float*)d_out;

    char* p = (char*)d_ws;
    auto alloc = [&](size_t bytes) { char* r = p; p += (bytes + 255) & ~(size_t)255; return r; };
    unsigned short* hb  = (unsigned short*)alloc((size_t)N_NODES * HC * 2);  // 51.2 MB
    float* xA   = (float*)alloc((size_t)N_NODES * CH * 4);
    float* xB   = (float*)alloc((size_t)N_NODES * CH * 4);
    float* es   = (float*)alloc((size_t)N_NODES * 4 * 4);
    float* ed   = (float*)alloc((size_t)N_NODES * 4 * 4);
    int* counts = (int*)alloc((size_t)N_NODES * 4);
    int* off    = (int*)alloc((size_t)(N_NODES + 1) * 4);
    int* fill   = (int*)alloc((size_t)N_NODES * 4);
    int* bsum   = (int*)alloc(512 * 4);
    int* flag   = (int*)alloc(256);
    int* src32  = (int*)alloc((size_t)N_TOT * 4);
    int* dst32  = (int*)alloc((size_t)N_TOT * 4);
    int* csr    = (int*)alloc((size_t)N_TOT * 4);

    int nbScan = (N_NODES + 255) / 256;   // 391
    int nchunk = (N_TOT + CHUNK_E - 1) / CHUNK_E;   // 104
    hipMemsetAsync(counts, 0, (size_t)N_NODES * 4, stream);
    detect_dtype<<<1, 64, 0, stream>>>((const int*)ei, flag);
    convert_hist_k<<<(N_TOT + 255) / 256, 256, 0, stream>>>(ei, flag, src32, dst32, counts);
    scan_block<<<nbScan, 256, 0, stream>>>(counts, off, bsum);
    scan_bsum<<<1, 512, 0, stream>>>(bsum, nbScan);
    scan_add<<<nbScan, 256, 0, stream>>>(off, bsum, fill);
    scatter_part_k<<<nchunk * NPART, 256, 0, stream>>>(src32, dst32, fill, csr);

    const float* xin = x0;
    const float* W = W0;
    float* xbufs[2] = {xA, xB};
    int ngemm = (N_NODES + 63) / 64;
    for (int l = 0; l < 3; ++l) {
        if (l == 0)
            gemm_mfma_k<128><<<ngemm, 256, 0, stream>>>(xin, W, asrc + l * HC, adst + l * HC, hb, es, ed);
        else
            gemm_mfma_k<64><<<ngemm, 256, 0, stream>>>(xin, W, asrc + l * HC, adst + l * HC, hb, es, ed);
        float* xo = xbufs[l & 1];
        aggregate_k<<<(N_NODES + 3) / 4, 256, 0, stream>>>(hb, es, ed, off, csr,
            cbias + l * CH, bng + l * CH, bnb + l * CH, bnm + l * CH, bnv + l * CH, xo);
        xin = xo;
        W = Wl + (size_t)l * CH * HC;
    }
    mlp_k<<<(N_NODES + 255) / 256, 256, 0, stream>>>(xin, l1w, l1b, l2w, l2b, out);
}

// Round 5
// 698.475 us; speedup vs baseline: 1.9733x; 1.0700x over previous
//
#include <hip/hip_runtime.h>
#include <hip/hip_bf16.h>
#include <cstdint>

#define N_NODES 100000
#define N_EDGES 1600000
#define N_TOT   1700000   // edges + self loops
#define HEADS   4
#define CH      64
#define HC      256       // HEADS*CH
#define NEG     0.2f
#define BNEPS   1e-5f
#define NPART   8
#define PART_N  12500     // N_NODES / NPART
#define CHUNK_E 16384

typedef __attribute__((ext_vector_type(8))) short short8;
typedef __attribute__((ext_vector_type(4))) float f32x4;

static __device__ __forceinline__ float lrelu(float x) {
    return x > 0.f ? x : NEG * x;
}
static __device__ __forceinline__ unsigned short f2bf(float f) {
    unsigned int u = __float_as_uint(f);
    unsigned int r = (u + 0x7fffu + ((u >> 16) & 1u)) >> 16;   // RNE
    return (unsigned short)r;
}
static __device__ __forceinline__ float bflo(unsigned int v) { return __uint_as_float(v << 16); }
static __device__ __forceinline__ float bfhi(unsigned int v) { return __uint_as_float(v & 0xffff0000u); }

// ---------------- fused dtype-detect + convert + histogram ----------------
__global__ void convert_hist_k(const void* ei,
                               int* __restrict__ src32, int* __restrict__ dst32,
                               int* __restrict__ counts) {
    // wave-local int64-vs-int32 detection: node ids < 2^17, so int64 odd words are 0
    const int* e32 = (const int*)ei;
    int l = threadIdx.x & 63;
    unsigned long long b = __ballot(e32[2 * l + 1] == 0);
    int is64 = (__popcll(b) >= 48) ? 1 : 0;

    int e = blockIdx.x * 256 + threadIdx.x;
    if (e >= N_TOT) return;
    int s, d;
    if (e < N_EDGES) {
        if (is64) {
            s = (int)((const long long*)ei)[e];
            d = (int)((const long long*)ei)[(long long)N_EDGES + e];
        } else {
            s = ((const int*)ei)[e];
            d = ((const int*)ei)[N_EDGES + e];
        }
    } else { int v = e - N_EDGES; s = v; d = v; }
    src32[e] = s; dst32[e] = d;
    atomicAdd(&counts[d], 1);
}

__global__ void scan_block(const int* in, int* out, int* bsum) {
    __shared__ int sm[256];
    int t = threadIdx.x;
    int i = blockIdx.x * 256 + t;
    int v = (i < N_NODES) ? in[i] : 0;
    int acc = v;
    sm[t] = v; __syncthreads();
    for (int d = 1; d < 256; d <<= 1) {
        int add = (t >= d) ? sm[t - d] : 0;
        __syncthreads();
        acc += add; sm[t] = acc;
        __syncthreads();
    }
    if (i < N_NODES) out[i] = acc - v;
    if (t == 255) bsum[blockIdx.x] = acc;
}

__global__ void scan_bsum(int* bsum, int nb) {
    __shared__ int sm[512];
    int t = threadIdx.x;
    int v = (t < nb) ? bsum[t] : 0;
    int acc = v;
    sm[t] = v; __syncthreads();
    for (int d = 1; d < 512; d <<= 1) {
        int add = (t >= d) ? sm[t - d] : 0;
        __syncthreads();
        acc += add; sm[t] = acc;
        __syncthreads();
    }
    if (t < nb) bsum[t] = acc - v;
}

__global__ void scan_add(int* off, const int* bsum, int* fill) {
    int i = blockIdx.x * 256 + threadIdx.x;
    if (i < N_NODES) {
        int v = off[i] + bsum[blockIdx.x];
        off[i] = v; fill[i] = v;
    }
    if (i == 0) off[N_NODES] = N_TOT;
}

// dst-partitioned scatter: partition p's csr range is written by blocks with blockIdx%8==p (one XCD)
__global__ void scatter_part_k(const int* __restrict__ src32, const int* __restrict__ dst32,
                               int* __restrict__ fill, int* __restrict__ csr) {
    int part = blockIdx.x & (NPART - 1), chunk = blockIdx.x / NPART;
    int lo = part * PART_N, hi = lo + PART_N;
    int base = chunk * CHUNK_E;
    int end = min(base + CHUNK_E, N_TOT);
    for (int i = base + threadIdx.x; i < end; i += 256) {
        int d = dst32[i];
        if (d >= lo && d < hi) {
            int s = src32[i];
            int pos = atomicAdd(&fill[d], 1);
            csr[pos] = s;
        }
    }
}

// ---- MFMA bf16 GEMM: H = A @ W[K,256], multi-tile per block (W staged once) ----
// fused: bf16 h store (coalesced via LDS repack) + per-head attention logits
template<int K, bool ABF16>
__global__ __launch_bounds__(256) void gemm_mfma_k(const void* __restrict__ Ain,
                                                   const float* __restrict__ Wf,
                                                   const float* __restrict__ as,
                                                   const float* __restrict__ ad,
                                                   unsigned short* __restrict__ hb,
                                                   float* __restrict__ es,
                                                   float* __restrict__ ed, int ntiles) {
    __shared__ __align__(16) unsigned short Bs[256 * K];   // [col][k], XOR-swizzled
    __shared__ __align__(16) unsigned short As[64 * K];    // [row][k], XOR-swizzled; scratch in epilogue
    int t = threadIdx.x;

    // stage B once: fp32 W -> bf16 transposed LDS
    for (int idx4 = t; idx4 < K * 64; idx4 += 256) {
        int k = idx4 >> 6;
        int c = (idx4 & 63) * 4;
        float4 wv = *(const float4*)(Wf + (size_t)k * HC + c);
        Bs[((c + 0) * K + k) ^ (((c + 0) & 7) << 3)] = f2bf(wv.x);
        Bs[((c + 1) * K + k) ^ (((c + 1) & 7) << 3)] = f2bf(wv.y);
        Bs[((c + 2) * K + k) ^ (((c + 2) & 7) << 3)] = f2bf(wv.z);
        Bs[((c + 3) * K + k) ^ (((c + 3) & 7) << 3)] = f2bf(wv.w);
    }

    int w = t >> 6, lane = t & 63;
    int c16 = lane & 15, kg = lane >> 4;
    int swz = (c16 & 7) << 3;
    float asv[4], adv[4];
    #pragma unroll
    for (int ct = 0; ct < 4; ++ct) {
        asv[ct] = as[w * 64 + ct * 16 + c16];
        adv[ct] = ad[w * 64 + ct * 16 + c16];
    }
    __syncthreads();

    for (int tile = blockIdx.x; tile < ntiles; tile += gridDim.x) {
        int bm = tile * 64;
        // ---- stage A (64 rows x K) ----
        #pragma unroll
        for (int i = 0; i < (64 * K / 8) / 256; ++i) {
            int cidx = i * 256 + t;
            int row = cidx / (K / 8);
            int ks = (cidx % (K / 8)) * 8;
            int grow = bm + row;
            uint4 pk = make_uint4(0, 0, 0, 0);
            if (grow < N_NODES) {
                if (ABF16) {
                    pk = *(const uint4*)((const unsigned short*)Ain + (size_t)grow * K + ks);
                } else {
                    const float* Af = (const float*)Ain + (size_t)grow * K + ks;
                    float4 v0 = *(const float4*)Af;
                    float4 v1 = *(const float4*)(Af + 4);
                    pk.x = (unsigned)f2bf(v0.x) | ((unsigned)f2bf(v0.y) << 16);
                    pk.y = (unsigned)f2bf(v0.z) | ((unsigned)f2bf(v0.w) << 16);
                    pk.z = (unsigned)f2bf(v1.x) | ((unsigned)f2bf(v1.y) << 16);
                    pk.w = (unsigned)f2bf(v1.z) | ((unsigned)f2bf(v1.w) << 16);
                }
            }
            *(uint4*)(&As[(row * K + ks) ^ ((row & 7) << 3)]) = pk;
        }
        __syncthreads();

        // ---- MFMA K-loop ----
        f32x4 acc[4][4];
        #pragma unroll
        for (int i = 0; i < 4; ++i)
            #pragma unroll
            for (int j = 0; j < 4; ++j) acc[i][j] = (f32x4)(0.f);

        #pragma unroll
        for (int kc = 0; kc < K / 32; ++kc) {
            int ko = kc * 32 + kg * 8;
            short8 af[4], bf[4];
            #pragma unroll
            for (int rs = 0; rs < 4; ++rs)
                af[rs] = *(const short8*)(&As[((16 * rs + c16) * K + ko) ^ swz]);
            #pragma unroll
            for (int ct = 0; ct < 4; ++ct) {
                int col = w * 64 + ct * 16 + c16;
                bf[ct] = *(const short8*)(&Bs[(col * K + ko) ^ swz]);
            }
            #pragma unroll
            for (int rs = 0; rs < 4; ++rs)
                #pragma unroll
                for (int ct = 0; ct < 4; ++ct)
                    acc[rs][ct] = __builtin_amdgcn_mfma_f32_16x16x32_bf16(af[rs], bf[ct], acc[rs][ct], 0, 0, 0);
        }

        // ---- logits epilogue (fp32 accumulators) ----
        #pragma unroll
        for (int rs = 0; rs < 4; ++rs) {
            float esr[4], edr[4];
            #pragma unroll
            for (int reg = 0; reg < 4; ++reg) {
                float s = 0.f, d = 0.f;
                #pragma unroll
                for (int ct = 0; ct < 4; ++ct) {
                    s += acc[rs][ct][reg] * asv[ct];
                    d += acc[rs][ct][reg] * adv[ct];
                }
                #pragma unroll
                for (int sh = 1; sh < 16; sh <<= 1) {
                    s += __shfl_xor(s, sh);
                    d += __shfl_xor(d, sh);
                }
                esr[reg] = s; edr[reg] = d;
            }
            if (c16 == 0) {
                int r0 = bm + rs * 16 + kg * 4;
                #pragma unroll
                for (int reg = 0; reg < 4; ++reg) {
                    if (r0 + reg < N_NODES) {
                        es[(size_t)(r0 + reg) * 4 + w] = esr[reg];
                        ed[(size_t)(r0 + reg) * 4 + w] = edr[reg];
                    }
                }
            }
        }
        __syncthreads();   // all As reads done -> reuse as repack scratch

        // ---- h store: repack 16 rows at a time through As, coalesced uint4 stores ----
        #pragma unroll
        for (int rs = 0; rs < 4; ++rs) {
            #pragma unroll
            for (int ct = 0; ct < 4; ++ct)
                #pragma unroll
                for (int reg = 0; reg < 4; ++reg)
                    As[(kg * 4 + reg) * 256 + w * 64 + ct * 16 + c16] = f2bf(acc[rs][ct][reg]);
            __syncthreads();
            int row16 = t >> 4, cseg = (t & 15) * 16;
            int grow = bm + rs * 16 + row16;
            if (grow < N_NODES) {
                uint4 v0 = *(const uint4*)(&As[row16 * 256 + cseg]);
                uint4 v1 = *(const uint4*)(&As[row16 * 256 + cseg + 8]);
                *(uint4*)(hb + (size_t)grow * HC + cseg) = v0;
                *(uint4*)(hb + (size_t)grow * HC + cseg + 8) = v1;
            }
            __syncthreads();
        }
    }
}

// ---- aggregation: edge softmax + weighted bf16 gather + BN + ReLU ----
template<bool OUTBF16>
__global__ __launch_bounds__(256) void aggregate_k(const unsigned short* __restrict__ h,
                                                   const float* __restrict__ es,
                                                   const float* __restrict__ ed,
                                                   const int* __restrict__ off,
                                                   const int* __restrict__ csr,
                                                   const float* __restrict__ bias,
                                                   const float* __restrict__ g,
                                                   const float* __restrict__ bb,
                                                   const float* __restrict__ mu,
                                                   const float* __restrict__ var,
                                                   void* __restrict__ xout) {
    __shared__ float wbuf[4][64][4];
    __shared__ int   sbuf[4][64];
    int wv = threadIdx.x >> 6;
    int lane = threadIdx.x & 63;
    int wid = blockIdx.x * 4 + wv;
    if (wid >= N_NODES) return;   // wave-uniform exit, no block barriers below

    int s0 = off[wid], s1 = off[wid + 1];
    float4 edv = *(const float4*)(ed + (size_t)wid * 4);

    int half = lane >> 5;          // which edge of the pair
    int sub  = lane & 31;          // 32 lanes cover one 512B bf16 row
    int head = sub >> 3;           // 8 lanes per head
    float ds0 = 0.f, ds1 = 0.f, ds2 = 0.f, ds3 = 0.f;
    float a0 = 0.f, a1 = 0.f, a2 = 0.f, a3 = 0.f, a4 = 0.f, a5 = 0.f, a6 = 0.f, a7 = 0.f;
    const unsigned short* hsub = h + sub * 8;

    for (int base = s0; base < s1; base += 64) {
        int e = base + lane;
        float w0 = 0.f, w1 = 0.f, w2 = 0.f, w3 = 0.f;
        int s = 0;
        if (e < s1) {
            s = csr[e];
            float4 ev = *(const float4*)(es + (size_t)s * 4);
            w0 = __expf(fminf(lrelu(ev.x + edv.x), 80.f));
            w1 = __expf(fminf(lrelu(ev.y + edv.y), 80.f));
            w2 = __expf(fminf(lrelu(ev.z + edv.z), 80.f));
            w3 = __expf(fminf(lrelu(ev.w + edv.w), 80.f));
        }
        ds0 += w0; ds1 += w1; ds2 += w2; ds3 += w3;
        *(float4*)(&wbuf[wv][lane][0]) = make_float4(w0, w1, w2, w3);
        sbuf[wv][lane] = s;
        asm volatile("" ::: "memory");   // wave-synchronous LDS ordering

        int cnt = min(64, s1 - base);
        int jj = half;
        int scur = (jj < cnt) ? sbuf[wv][jj] : sbuf[wv][0];
        float wcur = (jj < cnt) ? wbuf[wv][jj][head] : 0.f;
        uint4 hv = *(const uint4*)(hsub + (size_t)scur * HC);
        for (int j = 0; j < cnt; j += 2) {
            int jn = j + 2 + half;
            int snx = (jn < cnt) ? sbuf[wv][jn] : sbuf[wv][0];
            float wnx = (jn < cnt) ? wbuf[wv][jn][head] : 0.f;
            uint4 hn = *(const uint4*)(hsub + (size_t)snx * HC);   // prefetch next pair
            a0 = fmaf(wcur, bflo(hv.x), a0); a1 = fmaf(wcur, bfhi(hv.x), a1);
            a2 = fmaf(wcur, bflo(hv.y), a2); a3 = fmaf(wcur, bfhi(hv.y), a3);
            a4 = fmaf(wcur, bflo(hv.z), a4); a5 = fmaf(wcur, bfhi(hv.z), a5);
            a6 = fmaf(wcur, bflo(hv.w), a6); a7 = fmaf(wcur, bfhi(hv.w), a7);
            hv = hn; wcur = wnx;
        }
        asm volatile("" ::: "memory");
    }

    a0 += __shfl_xor(a0, 32); a1 += __shfl_xor(a1, 32);
    a2 += __shfl_xor(a2, 32); a3 += __shfl_xor(a3, 32);
    a4 += __shfl_xor(a4, 32); a5 += __shfl_xor(a5, 32);
    a6 += __shfl_xor(a6, 32); a7 += __shfl_xor(a7, 32);

    #pragma unroll
    for (int d = 1; d < 64; d <<= 1) {
        ds0 += __shfl_xor(ds0, d); ds1 += __shfl_xor(ds1, d);
        ds2 += __shfl_xor(ds2, d); ds3 += __shfl_xor(ds3, d);
    }
    float den = head == 0 ? ds0 : head == 1 ? ds1 : head == 2 ? ds2 : ds3;
    float inv = 1.f / den;
    a0 *= inv; a1 *= inv; a2 *= inv; a3 *= inv;
    a4 *= inv; a5 *= inv; a6 *= inv; a7 *= inv;

    a0 += __shfl_xor(a0, 8);  a1 += __shfl_xor(a1, 8);
    a2 += __shfl_xor(a2, 8);  a3 += __shfl_xor(a3, 8);
    a4 += __shfl_xor(a4, 8);  a5 += __shfl_xor(a5, 8);
    a6 += __shfl_xor(a6, 8);  a7 += __shfl_xor(a7, 8);
    a0 += __shfl_xor(a0, 16); a1 += __shfl_xor(a1, 16);
    a2 += __shfl_xor(a2, 16); a3 += __shfl_xor(a3, 16);
    a4 += __shfl_xor(a4, 16); a5 += __shfl_xor(a5, 16);
    a6 += __shfl_xor(a6, 16); a7 += __shfl_xor(a7, 16);

    if (lane < 8) {
        int c = lane * 8;
        float av[8] = {a0, a1, a2, a3, a4, a5, a6, a7};
        float4 bi0 = *(const float4*)(bias + c), bi1 = *(const float4*)(bias + c + 4);
        float4 gv0 = *(const float4*)(g + c),    gv1 = *(const float4*)(g + c + 4);
        float4 bv0 = *(const float4*)(bb + c),   bv1 = *(const float4*)(bb + c + 4);
        float4 mv0 = *(const float4*)(mu + c),   mv1 = *(const float4*)(mu + c + 4);
        float4 vv0 = *(const float4*)(var + c),  vv1 = *(const float4*)(var + c + 4);
        float bia[8] = {bi0.x, bi0.y, bi0.z, bi0.w, bi1.x, bi1.y, bi1.z, bi1.w};
        float gg[8]  = {gv0.x, gv0.y, gv0.z, gv0.w, gv1.x, gv1.y, gv1.z, gv1.w};
        float be[8]  = {bv0.x, bv0.y, bv0.z, bv0.w, bv1.x, bv1.y, bv1.z, bv1.w};
        float mm[8]  = {mv0.x, mv0.y, mv0.z, mv0.w, mv1.x, mv1.y, mv1.z, mv1.w};
        float vv[8]  = {vv0.x, vv0.y, vv0.z, vv0.w, vv1.x, vv1.y, vv1.z, vv1.w};
        float o[8];
        #pragma unroll
        for (int k = 0; k < 8; ++k) {
            float t0 = (av[k] * 0.25f + bia[k] - mm[k]) * (gg[k] * rsqrtf(vv[k] + BNEPS)) + be[k];
            o[k] = fmaxf(t0, 0.f);
        }
        if (OUTBF16) {
            uint4 pk;
            pk.x = (unsigned)f2bf(o[0]) | ((unsigned)f2bf(o[1]) << 16);
            pk.y = (unsigned)f2bf(o[2]) | ((unsigned)f2bf(o[3]) << 16);
            pk.z = (unsigned)f2bf(o[4]) | ((unsigned)f2bf(o[5]) << 16);
            pk.w = (unsigned)f2bf(o[6]) | ((unsigned)f2bf(o[7]) << 16);
            *(uint4*)((unsigned short*)xout + (size_t)wid * CH + c) = pk;
        } else {
            *(float4*)((float*)xout + (size_t)wid * CH + c)     = make_float4(o[0], o[1], o[2], o[3]);
            *(float4*)((float*)xout + (size_t)wid * CH + c + 4) = make_float4(o[4], o[5], o[6], o[7]);
        }
    }
}

// ---------------- MLP head: out = relu(x@W1+b1)@W2+b2 ----------------
__global__ __launch_bounds__(256) void mlp_k(const float* __restrict__ x,
                                             const float* __restrict__ w1,
                                             const float* __restrict__ b1,
                                             const float* __restrict__ w2,
                                             const float* __restrict__ b2,
                                             float* __restrict__ out) {
    __shared__ float w1s[CH * 32];
    __shared__ float w2s[32];
    __shared__ float b1s[32];
    int t = threadIdx.x;
    for (int i = t; i < CH * 32; i += 256) w1s[i] = w1[i];
    if (t < 32) { w2s[t] = w2[t]; b1s[t] = b1[t]; }
    __syncthreads();
    int n = blockIdx.x * 256 + t;
    if (n >= N_NODES) return;
    float y[32];
    #pragma unroll
    for (int j = 0; j < 32; ++j) y[j] = b1s[j];
    const float* xr = x + (size_t)n * CH;
    for (int c4 = 0; c4 < 16; ++c4) {
        float4 xv = *(const float4*)(xr + c4 * 4);
        const float* wr = &w1s[c4 * 4 * 32];
        #pragma unroll
        for (int j = 0; j < 32; ++j)
            y[j] += xv.x * wr[j] + xv.y * wr[32 + j] + xv.z * wr[64 + j] + xv.w * wr[96 + j];
    }
    float o = b2[0];
    #pragma unroll
    for (int j = 0; j < 32; ++j) o += fmaxf(y[j], 0.f) * w2s[j];
    out[n] = o;
}

extern "C" void kernel_launch(void* const* d_in, const int* in_sizes, int n_in,
                              void* d_out, int out_size, void* d_ws, size_t ws_size,
                              hipStream_t stream) {
    const float* x0    = (const float*)d_in[0];
    const void*  ei    = d_in[1];
    const float* W0    = (const float*)d_in[2];
    const float* Wl    = (const float*)d_in[3];
    const float* asrc  = (const float*)d_in[4];
    const float* adst  = (const float*)d_in[5];
    const float* cbias = (const float*)d_in[6];
    const float* bng   = (const float*)d_in[7];
    const float* bnb   = (const float*)d_in[8];
    const float* bnm   = (const float*)d_in[9];
    const float* bnv   = (const float*)d_in[10];
    const float* l1w   = (const float*)d_in[11];
    const float* l1b   = (const float*)d_in[12];
    const float* l2w   = (const float*)d_in[13];
    const float* l2b   = (const float*)d_in[14];
    float* out = (float*)d_out;

    char* p = (char*)d_ws;
    auto alloc = [&](size_t bytes) { char* r = p; p += (bytes + 255) & ~(size_t)255; return r; };
    unsigned short* hb   = (unsigned short*)alloc((size_t)N_NODES * HC * 2);  // 51.2 MB
    unsigned short* xb0  = (unsigned short*)alloc((size_t)N_NODES * CH * 2);  // 12.8 MB
    unsigned short* xb1  = (unsigned short*)alloc((size_t)N_NODES * CH * 2);  // 12.8 MB
    float* xf32 = (float*)alloc((size_t)N_NODES * CH * 4);                    // 25.6 MB
    float* es   = (float*)alloc((size_t)N_NODES * 4 * 4);
    float* ed   = (float*)alloc((size_t)N_NODES * 4 * 4);
    int* counts = (int*)alloc((size_t)N_NODES * 4);
    int* off    = (int*)alloc((size_t)(N_NODES + 1) * 4);
    int* fill   = (int*)alloc((size_t)N_NODES * 4);
    int* bsum   = (int*)alloc(512 * 4);
    int* src32  = (int*)alloc((size_t)N_TOT * 4);
    int* dst32  = (int*)alloc((size_t)N_TOT * 4);
    int* csr    = (int*)alloc((size_t)N_TOT * 4);

    int nbScan = (N_NODES + 255) / 256;             // 391
    int nchunk = (N_TOT + CHUNK_E - 1) / CHUNK_E;   // 104
    int ntiles = (N_NODES + 63) / 64;               // 1563
    hipMemsetAsync(counts, 0, (size_t)N_NODES * 4, stream);
    convert_hist_k<<<(N_TOT + 255) / 256, 256, 0, stream>>>(ei, src32, dst32, counts);
    scan_block<<<nbScan, 256, 0, stream>>>(counts, off, bsum);
    scan_bsum<<<1, 512, 0, stream>>>(bsum, nbScan);
    scan_add<<<nbScan, 256, 0, stream>>>(off, bsum, fill);
    scatter_part_k<<<nchunk * NPART, 256, 0, stream>>>(src32, dst32, fill, csr);

    int nagg = (N_NODES + 3) / 4;
    // layer 0: fp32 x -> bf16 out
    gemm_mfma_k<128, false><<<512, 256, 0, stream>>>(x0, W0, asrc, adst, hb, es, ed, ntiles);
    aggregate_k<true><<<nagg, 256, 0, stream>>>(hb, es, ed, off, csr,
        cbias, bng, bnb, bnm, bnv, xb0);
    // layer 1: bf16 x -> bf16 out
    gemm_mfma_k<64, true><<<1024, 256, 0, stream>>>(xb0, Wl, asrc + HC, adst + HC, hb, es, ed, ntiles);
    aggregate_k<true><<<nagg, 256, 0, stream>>>(hb, es, ed, off, csr,
        cbias + CH, bng + CH, bnb + CH, bnm + CH, bnv + CH, xb1);
    // layer 2: bf16 x -> fp32 out (for MLP)
    gemm_mfma_k<64, true><<<1024, 256, 0, stream>>>(xb1, Wl + (size_t)CH * HC, asrc + 2 * HC, adst + 2 * HC, hb, es, ed, ntiles);
    aggregate_k<false><<<nagg, 256, 0, stream>>>(hb, es, ed, off, csr,
        cbias + 2 * CH, bng + 2 * CH, bnb + 2 * CH, bnm + 2 * CH, bnv + 2 * CH, xf32);

    mlp_k<<<(N_NODES + 255) / 256, 256, 0, stream>>>(xf32, l1w, l1b, l2w, l2b, out);
}